// Round 15
// baseline (236.968 us; speedup 1.0000x reference)
//
#include <hip/hip_runtime.h>
#include <hip/hip_fp16.h>

#define N_NODES 100000
#define N_EDGES 1600000
#define D 64

#define NB 256                  // fat buckets
#define BUCKET_W 391            // nodes per bucket (256*391 = 100096 >= 100000)
#define NB_USED 256
#define NBLK 256                // partition blocks (exact per-block regions)
#define CHUNK ((N_EDGES + NBLK - 1) / NBLK)             // 6250
#define CCAP 7168               // max edges per bucket (mean 6250, sd ~79)
#define LMASK 511               // 9-bit local node index

// ---------------- pass A: per-block LDS histogram -> gcount[b*NBLK+blk] ----------------
__global__ __launch_bounds__(256) void bucket_count(const int* __restrict__ dst,
                                                    int* __restrict__ gcount) {
    __shared__ int h[NB];
    if (threadIdx.x < NB) h[threadIdx.x] = 0;
    __syncthreads();
    const int blk = blockIdx.x;
    const int beg = blk * CHUNK;
    const int end = min(beg + CHUNK, N_EDGES);
    for (int e = beg + threadIdx.x; e < end; e += 256)
        atomicAdd(&h[dst[e] / BUCKET_W], 1);
    __syncthreads();
    if (threadIdx.x < NB)
        gcount[threadIdx.x * NBLK + blk] = h[threadIdx.x];   // exact, no global atomics
}

// ---------------- exact scan of 65536 (bucket,block) counts -> subbase ----------------
__global__ __launch_bounds__(1024) void scan64k(const int* __restrict__ gcount,
                                                int* __restrict__ subbase) {
    __shared__ int s[1024];
    const int t = threadIdx.x;
    int loc[64];
    int sum = 0;
#pragma unroll
    for (int i = 0; i < 64; ++i) { loc[i] = gcount[t * 64 + i]; sum += loc[i]; }
    s[t] = sum;
    __syncthreads();
    for (int off = 1; off < 1024; off <<= 1) {
        int u = (t >= off) ? s[t - off] : 0;
        __syncthreads();
        s[t] += u;
        __syncthreads();
    }
    int excl = s[t] - sum;
#pragma unroll
    for (int i = 0; i < 64; ++i) { subbase[t * 64 + i] = excl; excl += loc[i]; }
    if (t == 1023) subbase[NB * NBLK] = excl;   // == N_EDGES
}

// ---------------- pass B: partition with LDS cursors (no global atomics) ----------------
__global__ __launch_bounds__(256) void partition_edges(const int* __restrict__ src,
                                                       const int* __restrict__ dst,
                                                       const int* __restrict__ subbase,
                                                       int* __restrict__ part) {
    __shared__ int cur[NB];
    const int blk = blockIdx.x;
    if (threadIdx.x < NB) cur[threadIdx.x] = subbase[threadIdx.x * NBLK + blk];
    __syncthreads();
    const int beg = blk * CHUNK;
    const int end = min(beg + CHUNK, N_EDGES);
    for (int e = beg + threadIdx.x; e < end; e += 256) {
        const int d = dst[e];
        const int s = src[e];
        const int b = d / BUCKET_W;
        const int pos = atomicAdd(&cur[b], 1);          // LDS atomic
        part[pos] = (s << 9) | (d - b * BUCKET_W);      // ~24 edges/region: lines fill
    }
}

// ---------------- pass C: counting sort -> col, rowptr, dinv + fused convert_scale -----
__global__ __launch_bounds__(256) void bucket_csr(const int* __restrict__ subbase,
                                                  const int* __restrict__ part,
                                                  const float* __restrict__ feature,
                                                  int* __restrict__ col,
                                                  int* __restrict__ rowptr,
                                                  float* __restrict__ dinv,
                                                  __half* __restrict__ xh) {
    __shared__ int ed[CCAP];
    __shared__ int hist[BUCKET_W];
    __shared__ int offs[BUCKET_W];
    __shared__ int lcur[BUCKET_W];
    const int b = blockIdx.x;
    const int base = subbase[b * NBLK];
    const int cnt = min(subbase[(b + 1) * NBLK] - base, CCAP);
    const int n0 = b * BUCKET_W;
    const int nn = min(N_NODES - n0, BUCKET_W);
    const int t = threadIdx.x;

    for (int i = t; i < BUCKET_W; i += 256) hist[i] = 0;
    for (int i = t; i < cnt; i += 256) ed[i] = part[base + i];
    __syncthreads();
    for (int i = t; i < cnt; i += 256) atomicAdd(&hist[ed[i] & LMASK], 1);
    __syncthreads();
    if (t == 0) {
        int a = 0;
        for (int i = 0; i < nn; ++i) { offs[i] = a; lcur[i] = a; a += hist[i]; }
    }
    __syncthreads();
    for (int i = t; i < nn; i += 256) {
        rowptr[n0 + i] = base + offs[i];
        dinv[n0 + i] = rsqrtf((float)hist[i] + 1.0f);
    }
    if (b == NB_USED - 1 && t == 0) rowptr[N_NODES] = N_EDGES;
    __syncthreads();
    for (int i = t; i < cnt; i += 256) {
        const int p = ed[i];
        const int pos = atomicAdd(&lcur[p & LMASK], 1);
        col[base + pos] = p >> 9;
    }
    // fused convert_scale for this bucket's nodes: xh[n] = (half)(x[n]*dinv[n])
    const float2* f2 = (const float2*)feature;
    __half2* x2 = (__half2*)xh;
    for (int i = t; i < nn * 32; i += 256) {
        const int node = i >> 5, idx = i & 31;
        const float dv = rsqrtf((float)hist[node] + 1.0f);
        const float2 v = f2[(size_t)(n0 + node) * 32 + idx];
        x2[(size_t)(n0 + node) * 32 + idx] = __floats2half2_rn(v.x * dv, v.y * dv);
    }
}

// ---------------- fused layer: agg (2 nodes/wave) + GEMM (W in LDS) + relu -------------
__device__ __forceinline__ int rlane_i(int v, int l) {
    return __builtin_amdgcn_readlane(v, l);
}
__device__ __forceinline__ float rlane_ff(float v, int l) {
    return __int_as_float(__builtin_amdgcn_readlane(__float_as_int(v), l));
}

#define GATHER4(acc0, acc1, acc2, acc3, creg, tt)                         \
    {                                                                     \
        const int s0 = rlane_i(creg, tt + 0), s1 = rlane_i(creg, tt + 1); \
        const int s2 = rlane_i(creg, tt + 2), s3 = rlane_i(creg, tt + 3); \
        acc0 += __half2float(xh[(size_t)s0 * D + lane]);                  \
        acc1 += __half2float(xh[(size_t)s1 * D + lane]);                  \
        acc2 += __half2float(xh[(size_t)s2 * D + lane]);                  \
        acc3 += __half2float(xh[(size_t)s3 * D + lane]);                  \
    }

template <bool SCALED_HALF_OUT>
__global__ __launch_bounds__(256) void gcn_fused(const __half* __restrict__ xh,
                                                 const int* __restrict__ rowptr,
                                                 const int* __restrict__ col,
                                                 const float* __restrict__ dinv,
                                                 const float* __restrict__ W,
                                                 const float* __restrict__ bias,
                                                 float* __restrict__ out,
                                                 __half* __restrict__ outh, int npairs) {
    __shared__ float Ws[64 * 64];   // 16KB: Ws[k*64+f] = W[k][f]
    __shared__ float bs[64];
    for (int i = threadIdx.x; i < 64 * 64; i += 256) Ws[i] = W[i];
    if (threadIdx.x < 64) bs[threadIdx.x] = bias[threadIdx.x];
    __syncthreads();

    const int lane = threadIdx.x & 63;
    const int wv = threadIdx.x >> 6;
    const int stride = gridDim.x * 4;

    for (int pair = blockIdx.x * 4 + wv; pair < npairs; pair += stride) {
        const int nd0 = pair * 2, nd1 = nd0 + 1;
        const int b0 = rowptr[nd0];
        const int e0 = rowptr[nd0 + 1];
        const int e1 = rowptr[nd1 + 1];
        const int b1 = e0;                       // CSR rows are contiguous

        const int ch0 = min(e0 - b0, 64);
        const int ch1 = min(e1 - b1, 64);
        const int c0 = (lane < ch0) ? col[b0 + lane] : 0;   // both chunks in flight
        const int c1 = (lane < ch1) ? col[b1 + lane] : 0;

        float a0 = 0.f, a1 = 0.f, a2 = 0.f, a3 = 0.f;   // node0
        float d0 = 0.f, d1 = 0.f, d2 = 0.f, d3 = 0.f;   // node1

        const int m = min(ch0, ch1) & ~3;
        int t = 0;
        for (; t < m; t += 4) {              // interleaved: 8 independent gathers in flight
            GATHER4(a0, a1, a2, a3, c0, t)
            GATHER4(d0, d1, d2, d3, c1, t)
        }
        int t0 = t, t1 = t;
        for (; t0 + 3 < ch0; t0 += 4) GATHER4(a0, a1, a2, a3, c0, t0)
        for (; t0 < ch0; ++t0) a0 += __half2float(xh[(size_t)rlane_i(c0, t0) * D + lane]);
        for (; t1 + 3 < ch1; t1 += 4) GATHER4(d0, d1, d2, d3, c1, t1)
        for (; t1 < ch1; ++t1) d0 += __half2float(xh[(size_t)rlane_i(c1, t1) * D + lane]);

        // residual chunks for degree > 64 (essentially never for Poisson(16))
        for (int j = b0 + 64; j < e0; j += 64) {
            const int chunk = min(e0 - j, 64);
            const int c = (lane < chunk) ? col[j + lane] : 0;
            int tt = 0;
            for (; tt + 3 < chunk; tt += 4) GATHER4(a0, a1, a2, a3, c, tt)
            for (; tt < chunk; ++tt) a0 += __half2float(xh[(size_t)rlane_i(c, tt) * D + lane]);
        }
        for (int j = b1 + 64; j < e1; j += 64) {
            const int chunk = min(e1 - j, 64);
            const int c = (lane < chunk) ? col[j + lane] : 0;
            int tt = 0;
            for (; tt + 3 < chunk; tt += 4) GATHER4(d0, d1, d2, d3, c, tt)
            for (; tt < chunk; ++tt) d0 += __half2float(xh[(size_t)rlane_i(c, tt) * D + lane]);
        }

        const float dv0 = dinv[nd0], dv1 = dinv[nd1];
        const float self0 = __half2float(xh[(size_t)nd0 * D + lane]);
        const float self1 = __half2float(xh[(size_t)nd1 * D + lane]);
        const float a = dv0 * ((a0 + a1) + (a2 + a3) + self0);   // agg row, in registers
        const float d = dv1 * ((d0 + d1) + (d2 + d3) + self1);

        // GEMM: one LDS W-load serves both nodes (2 FMA per load)
        float g0 = 0.f, g1 = 0.f, h0 = 0.f, h1 = 0.f;
#pragma unroll
        for (int k = 0; k < 64; k += 2) {
            const float wk0 = Ws[k * 64 + lane];         // 2 lanes/bank: conflict-free
            const float wk1 = Ws[(k + 1) * 64 + lane];
            g0 = fmaf(rlane_ff(a, k), wk0, g0);
            h0 = fmaf(rlane_ff(d, k), wk0, h0);
            g1 = fmaf(rlane_ff(a, k + 1), wk1, g1);
            h1 = fmaf(rlane_ff(d, k + 1), wk1, h1);
        }
        const float r0 = fmaxf(g0 + g1 + bs[lane], 0.f);
        const float r1 = fmaxf(h0 + h1 + bs[lane], 0.f);
        if (SCALED_HALF_OUT) {
            outh[(size_t)nd0 * D + lane] = __float2half(r0 * dv0);  // pre-scaled next input
            outh[(size_t)nd1 * D + lane] = __float2half(r1 * dv1);
        } else {
            out[(size_t)nd0 * D + lane] = r0;
            out[(size_t)nd1 * D + lane] = r1;
        }
    }
}

extern "C" void kernel_launch(void* const* d_in, const int* in_sizes, int n_in,
                              void* d_out, int out_size, void* d_ws, size_t ws_size,
                              hipStream_t stream) {
    const float* feature = (const float*)d_in[0];
    const int*   edges   = (const int*)d_in[1];   // [2, E] flat: src then dst
    const float* W1      = (const float*)d_in[2];
    const float* b1      = (const float*)d_in[3];
    const float* W2      = (const float*)d_in[4];
    const float* b2      = (const float*)d_in[5];
    float* out = (float*)d_out;

    const int* src = edges;
    const int* dst = edges + N_EDGES;

    // workspace layout (~40MB)
    char* w = (char*)d_ws;
    int*    gcount  = (int*)w;    w += sizeof(int) * (NB * NBLK);       // 65536
    int*    subbase = (int*)w;    w += sizeof(int) * (NB * NBLK + 1);   // 65537
    int*    rowptr  = (int*)w;    w += sizeof(int) * (N_NODES + 1);
    float*  dinv    = (float*)w;  w += sizeof(float) * (N_NODES);
    int*    part    = (int*)w;    w += sizeof(int) * (N_EDGES);          // 6.4MB
    int*    colA    = (int*)w;    w += sizeof(int) * (N_EDGES);          // 6.4MB
    __half* xh      = (__half*)w; w += sizeof(__half) * ((size_t)N_NODES * D);  // 12.8MB
    __half* y1h     = (__half*)w; w += sizeof(__half) * ((size_t)N_NODES * D);  // 12.8MB

    // ---- partition + CSR + fused scaled-fp16 conversion (once) ----
    bucket_count<<<NBLK, 256, 0, stream>>>(dst, gcount);
    scan64k<<<1, 1024, 0, stream>>>(gcount, subbase);
    partition_edges<<<NBLK, 256, 0, stream>>>(src, dst, subbase, part);
    bucket_csr<<<NB_USED, 256, 0, stream>>>(subbase, part, feature, colA, rowptr, dinv, xh);

    const int npairs = N_NODES / 2;   // 50000

    // ---- fused layers: (agg + GEMM + relu) x2 ----
    gcn_fused<true><<<2048, 256, 0, stream>>>(xh, rowptr, colA, dinv, W1, b1,
                                              nullptr, y1h, npairs);
    gcn_fused<false><<<2048, 256, 0, stream>>>(y1h, rowptr, colA, dinv, W2, b2,
                                               out, nullptr, npairs);
}

// Round 16
// 212.123 us; speedup vs baseline: 1.1171x; 1.1171x over previous
//
#include <hip/hip_runtime.h>
#include <hip/hip_fp16.h>

#define N_NODES 100000
#define N_EDGES 1600000
#define D 64

#define NB 256                  // fat buckets
#define BUCKET_W 391            // nodes per bucket (256*391 = 100096 >= 100000)
#define NB_USED 256
#define NBLK 256                // partition blocks (exact per-block regions)
#define CHUNK ((N_EDGES + NBLK - 1) / NBLK)             // 6250
#define CCAP 7168               // max edges per bucket (mean 6250, sd ~79)
#define LMASK 511               // 9-bit local node index

// ---------------- pass A: per-block LDS histogram -> gcount[b*NBLK+blk] ----------------
__global__ __launch_bounds__(1024) void bucket_count(const int* __restrict__ dst,
                                                     int* __restrict__ gcount) {
    __shared__ int h[NB];
    if (threadIdx.x < NB) h[threadIdx.x] = 0;
    __syncthreads();
    const int blk = blockIdx.x;
    const int beg = blk * CHUNK;
    const int end = min(beg + CHUNK, N_EDGES);
    for (int e = beg + threadIdx.x; e < end; e += 1024)
        atomicAdd(&h[dst[e] / BUCKET_W], 1);
    __syncthreads();
    if (threadIdx.x < NB)
        gcount[threadIdx.x * NBLK + blk] = h[threadIdx.x];   // exact, no global atomics
}

// ---------------- exact scan of 65536 (bucket,block) counts -> subbase ----------------
__global__ __launch_bounds__(1024) void scan64k(const int* __restrict__ gcount,
                                                int* __restrict__ subbase) {
    __shared__ int s[1024];
    const int t = threadIdx.x;
    int loc[64];
    int sum = 0;
#pragma unroll
    for (int i = 0; i < 64; ++i) { loc[i] = gcount[t * 64 + i]; sum += loc[i]; }
    s[t] = sum;
    __syncthreads();
    for (int off = 1; off < 1024; off <<= 1) {
        int u = (t >= off) ? s[t - off] : 0;
        __syncthreads();
        s[t] += u;
        __syncthreads();
    }
    int excl = s[t] - sum;
#pragma unroll
    for (int i = 0; i < 64; ++i) { subbase[t * 64 + i] = excl; excl += loc[i]; }
    if (t == 1023) subbase[NB * NBLK] = excl;   // == N_EDGES
}

// ---------------- pass B: partition with LDS cursors (no global atomics) ----------------
__global__ __launch_bounds__(1024) void partition_edges(const int* __restrict__ src,
                                                        const int* __restrict__ dst,
                                                        const int* __restrict__ subbase,
                                                        int* __restrict__ part) {
    __shared__ int cur[NB];
    const int blk = blockIdx.x;
    if (threadIdx.x < NB) cur[threadIdx.x] = subbase[threadIdx.x * NBLK + blk];
    __syncthreads();
    const int beg = blk * CHUNK;
    const int end = min(beg + CHUNK, N_EDGES);
    for (int e = beg + threadIdx.x; e < end; e += 1024) {
        const int d = dst[e];
        const int s = src[e];
        const int b = d / BUCKET_W;
        const int pos = atomicAdd(&cur[b], 1);          // LDS atomic
        part[pos] = (s << 9) | (d - b * BUCKET_W);      // ~24 edges/region: lines fill
    }
}

// ---------------- pass C: counting sort (parallel scan) + fused convert_scale ----------
__global__ __launch_bounds__(512) void bucket_csr(const int* __restrict__ subbase,
                                                  const int* __restrict__ part,
                                                  const float* __restrict__ feature,
                                                  int* __restrict__ col,
                                                  int* __restrict__ rowptr,
                                                  float* __restrict__ dinv,
                                                  __half* __restrict__ xh) {
    __shared__ int ed[CCAP];
    __shared__ int hist[BUCKET_W];
    __shared__ int lcur[BUCKET_W];
    __shared__ int sc[512];
    const int b = blockIdx.x;
    const int base = subbase[b * NBLK];
    const int cnt = min(subbase[(b + 1) * NBLK] - base, CCAP);
    const int n0 = b * BUCKET_W;
    const int nn = min(N_NODES - n0, BUCKET_W);
    const int t = threadIdx.x;

    if (t < BUCKET_W) hist[t] = 0;
    for (int i = t; i < cnt; i += 512) ed[i] = part[base + i];
    __syncthreads();
    for (int i = t; i < cnt; i += 512) atomicAdd(&hist[ed[i] & LMASK], 1);
    __syncthreads();
    // parallel exclusive scan of hist[0..nn) (nn <= 391 < 512)
    const int v = (t < nn) ? hist[t] : 0;
    sc[t] = v;
    __syncthreads();
    for (int off = 1; off < 512; off <<= 1) {
        int u = (t >= off) ? sc[t - off] : 0;
        __syncthreads();
        sc[t] += u;
        __syncthreads();
    }
    if (t < nn) {
        const int excl = sc[t] - v;
        lcur[t] = excl;
        rowptr[n0 + t] = base + excl;
        dinv[n0 + t] = rsqrtf((float)hist[t] + 1.0f);
    }
    if (b == NB_USED - 1 && t == 0) rowptr[N_NODES] = N_EDGES;
    __syncthreads();
    for (int i = t; i < cnt; i += 512) {
        const int p = ed[i];
        const int pos = atomicAdd(&lcur[p & LMASK], 1);
        col[base + pos] = p >> 9;
    }
    // fused convert_scale for this bucket's nodes: xh[n] = (half)(x[n]*dinv[n])
    const float2* f2 = (const float2*)feature;
    __half2* x2 = (__half2*)xh;
    for (int i = t; i < nn * 32; i += 512) {
        const int node = i >> 5, idx = i & 31;
        const float dv = rsqrtf((float)hist[node] + 1.0f);
        const float2 u = f2[(size_t)(n0 + node) * 32 + idx];
        x2[(size_t)(n0 + node) * 32 + idx] = __floats2half2_rn(u.x * dv, u.y * dv);
    }
}

// ---------------- aggregation, 2 nodes per wave (interleaved gather streams) -----------
__device__ __forceinline__ int rlane_i(int v, int l) {
    return __builtin_amdgcn_readlane(v, l);
}

#define GATHER4(acc0, acc1, acc2, acc3, creg, tt)                         \
    {                                                                     \
        const int s0 = rlane_i(creg, tt + 0), s1 = rlane_i(creg, tt + 1); \
        const int s2 = rlane_i(creg, tt + 2), s3 = rlane_i(creg, tt + 3); \
        acc0 += __half2float(xh[(size_t)s0 * D + lane]);                  \
        acc1 += __half2float(xh[(size_t)s1 * D + lane]);                  \
        acc2 += __half2float(xh[(size_t)s2 * D + lane]);                  \
        acc3 += __half2float(xh[(size_t)s3 * D + lane]);                  \
    }

__global__ __launch_bounds__(256) void agg_pair(const __half* __restrict__ xh,
                                                const int* __restrict__ rowptr,
                                                const int* __restrict__ col,
                                                const float* __restrict__ dinv,
                                                __half* __restrict__ aggh, int n) {
    const int gwave = (blockIdx.x * blockDim.x + threadIdx.x) >> 6;
    const int lane = threadIdx.x & 63;
    const int nd0 = gwave * 2;
    if (nd0 >= n) return;
    const int nd1 = nd0 + 1;
    const bool has1 = nd1 < n;

    const int b0 = rowptr[nd0];
    const int e0 = rowptr[nd0 + 1];
    const int e1 = has1 ? rowptr[nd1 + 1] : e0;
    const int b1 = e0;                       // CSR rows are contiguous

    const int ch0 = min(e0 - b0, 64);
    const int ch1 = min(e1 - b1, 64);
    const int c0 = (lane < ch0) ? col[b0 + lane] : 0;   // both chunks in flight
    const int c1 = (lane < ch1) ? col[b1 + lane] : 0;

    float a0 = 0.f, a1 = 0.f, a2 = 0.f, a3 = 0.f;   // node0
    float d0 = 0.f, d1 = 0.f, d2 = 0.f, d3 = 0.f;   // node1

    const int m = min(ch0, ch1) & ~3;
    int t = 0;
    for (; t < m; t += 4) {                 // interleaved: 8 independent gathers in flight
        GATHER4(a0, a1, a2, a3, c0, t)
        GATHER4(d0, d1, d2, d3, c1, t)
    }
    int t0 = t, t1 = t;
    for (; t0 + 3 < ch0; t0 += 4) GATHER4(a0, a1, a2, a3, c0, t0)
    for (; t0 < ch0; ++t0) a0 += __half2float(xh[(size_t)rlane_i(c0, t0) * D + lane]);
    for (; t1 + 3 < ch1; t1 += 4) GATHER4(d0, d1, d2, d3, c1, t1)
    for (; t1 < ch1; ++t1) d0 += __half2float(xh[(size_t)rlane_i(c1, t1) * D + lane]);

    // residual chunks for degree > 64 (essentially never for Poisson(16); kept for safety)
    for (int j = b0 + 64; j < e0; j += 64) {
        const int chunk = min(e0 - j, 64);
        const int c = (lane < chunk) ? col[j + lane] : 0;
        int tt = 0;
        for (; tt + 3 < chunk; tt += 4) GATHER4(a0, a1, a2, a3, c, tt)
        for (; tt < chunk; ++tt) a0 += __half2float(xh[(size_t)rlane_i(c, tt) * D + lane]);
    }
    for (int j = b1 + 64; j < e1; j += 64) {
        const int chunk = min(e1 - j, 64);
        const int c = (lane < chunk) ? col[j + lane] : 0;
        int tt = 0;
        for (; tt + 3 < chunk; tt += 4) GATHER4(d0, d1, d2, d3, c, tt)
        for (; tt < chunk; ++tt) d0 += __half2float(xh[(size_t)rlane_i(c, tt) * D + lane]);
    }

    const float self0 = __half2float(xh[(size_t)nd0 * D + lane]);
    aggh[(size_t)nd0 * D + lane] =
        __float2half(dinv[nd0] * ((a0 + a1) + (a2 + a3) + self0));
    if (has1) {
        const float self1 = __half2float(xh[(size_t)nd1 * D + lane]);
        aggh[(size_t)nd1 * D + lane] =
            __float2half(dinv[nd1] * ((d0 + d1) + (d2 + d3) + self1));
    }
}

// ---------------- GEMM: r = relu(agg @ W + b); write fp32 or scaled-fp16 ----------------
__device__ __forceinline__ float rlane_ff(float v, int l) {
    return __int_as_float(__builtin_amdgcn_readlane(__float_as_int(v), l));
}

template <bool SCALED_HALF_OUT>
__global__ __launch_bounds__(256) void gemm64(const __half* __restrict__ aggh,
                                              const float* __restrict__ W,
                                              const float* __restrict__ bias,
                                              const float* __restrict__ dinv,
                                              float* __restrict__ out,
                                              __half* __restrict__ outh, int n) {
    const int lane = threadIdx.x & 63;
    const int gwave = (blockIdx.x * blockDim.x + threadIdx.x) >> 6;
    const int nwaves = (gridDim.x * blockDim.x) >> 6;
    float wcol[64];
#pragma unroll
    for (int k = 0; k < 64; ++k) wcol[k] = W[k * 64 + lane];
    const float bv = bias[lane];

    for (int nd = gwave; nd < n; nd += nwaves) {
        const float a = __half2float(aggh[(size_t)nd * D + lane]);
        float g0 = 0.f, g1 = 0.f, g2 = 0.f, g3 = 0.f;
#pragma unroll
        for (int k = 0; k < 64; k += 4) {
            g0 = fmaf(rlane_ff(a, k + 0), wcol[k + 0], g0);
            g1 = fmaf(rlane_ff(a, k + 1), wcol[k + 1], g1);
            g2 = fmaf(rlane_ff(a, k + 2), wcol[k + 2], g2);
            g3 = fmaf(rlane_ff(a, k + 3), wcol[k + 3], g3);
        }
        const float r = fmaxf((g0 + g1) + (g2 + g3) + bv, 0.f);
        if (SCALED_HALF_OUT)
            outh[(size_t)nd * D + lane] = __float2half(r * dinv[nd]);
        else
            out[(size_t)nd * D + lane] = r;
    }
}

extern "C" void kernel_launch(void* const* d_in, const int* in_sizes, int n_in,
                              void* d_out, int out_size, void* d_ws, size_t ws_size,
                              hipStream_t stream) {
    const float* feature = (const float*)d_in[0];
    const int*   edges   = (const int*)d_in[1];   // [2, E] flat: src then dst
    const float* W1      = (const float*)d_in[2];
    const float* b1      = (const float*)d_in[3];
    const float* W2      = (const float*)d_in[4];
    const float* b2      = (const float*)d_in[5];
    float* out = (float*)d_out;

    const int* src = edges;
    const int* dst = edges + N_EDGES;

    // workspace layout (~53MB)
    char* w = (char*)d_ws;
    int*    gcount  = (int*)w;    w += sizeof(int) * (NB * NBLK);       // 65536
    int*    subbase = (int*)w;    w += sizeof(int) * (NB * NBLK + 1);   // 65537
    int*    rowptr  = (int*)w;    w += sizeof(int) * (N_NODES + 1);
    float*  dinv    = (float*)w;  w += sizeof(float) * (N_NODES);
    int*    part    = (int*)w;    w += sizeof(int) * (N_EDGES);          // 6.4MB
    int*    colA    = (int*)w;    w += sizeof(int) * (N_EDGES);          // 6.4MB
    __half* xh      = (__half*)w; w += sizeof(__half) * ((size_t)N_NODES * D);  // 12.8MB
    __half* y1h     = (__half*)w; w += sizeof(__half) * ((size_t)N_NODES * D);  // 12.8MB
    __half* aggh    = (__half*)w; w += sizeof(__half) * ((size_t)N_NODES * D);  // 12.8MB

    // ---- partition + CSR + fused scaled-fp16 conversion (once) ----
    bucket_count<<<NBLK, 1024, 0, stream>>>(dst, gcount);
    scan64k<<<1, 1024, 0, stream>>>(gcount, subbase);
    partition_edges<<<NBLK, 1024, 0, stream>>>(src, dst, subbase, part);
    bucket_csr<<<NB_USED, 512, 0, stream>>>(subbase, part, feature, colA, rowptr, dinv, xh);

    const int pair_blocks = (N_NODES / 2 + 3) / 4;   // 2 nodes/wave, 4 waves/block

    // ---- layer 1 ----
    agg_pair<<<pair_blocks, 256, 0, stream>>>(xh, rowptr, colA, dinv, aggh, N_NODES);
    gemm64<true><<<2048, 256, 0, stream>>>(aggh, W1, b1, dinv, nullptr, y1h, N_NODES);

    // ---- layer 2 ----
    agg_pair<<<pair_blocks, 256, 0, stream>>>(y1h, rowptr, colA, dinv, aggh, N_NODES);
    gemm64<false><<<2048, 256, 0, stream>>>(aggh, W2, b2, dinv, out, nullptr, N_NODES);
}

// Round 17
// 177.794 us; speedup vs baseline: 1.3328x; 1.1931x over previous
//
#include <hip/hip_runtime.h>
#include <hip/hip_fp16.h>

#define N_NODES 100000
#define N_EDGES 1600000
#define D 64

#define NB 256                  // fat buckets
#define BUCKET_W 391            // nodes per bucket (256*391 = 100096 >= 100000)
#define NB_USED 256
#define NBLK 256                // partition blocks
#define CHUNK ((N_EDGES + NBLK - 1) / NBLK)             // 6250
#define CCAP 7168               // fixed bucket capacity (mean 6250, sd ~79 -> 11 sigma)
#define LMASK 511               // 9-bit local node index

// ---------------- fused count+reserve+scatter: one pass, no scan kernel ----------------
// Each block: LDS histogram of its chunk -> one returning global atomicAdd per bucket
// (cursor[b] on its own 64B line) reserves a contiguous range in part[b*CCAP ...] ->
// LDS-cursor scatter (write locality preserved: ~24-edge runs per bucket-block).
__global__ __launch_bounds__(1024) void partition_fused(const int* __restrict__ src,
                                                        const int* __restrict__ dst,
                                                        int* __restrict__ cursor,
                                                        int* __restrict__ part) {
    __shared__ int h[NB];
    __shared__ int lcur[NB];
    const int t = threadIdx.x;
    if (t < NB) h[t] = 0;
    __syncthreads();
    const int blk = blockIdx.x;
    const int beg = blk * CHUNK;
    const int end = min(beg + CHUNK, N_EDGES);
    for (int e = beg + t; e < end; e += 1024)
        atomicAdd(&h[dst[e] / BUCKET_W], 1);
    __syncthreads();
    if (t < NB) {
        const int c = h[t];
        const int base = c ? atomicAdd(&cursor[t * 16], c) : 0;   // padded counter line
        lcur[t] = t * CCAP + base;
    }
    __syncthreads();
    for (int e = beg + t; e < end; e += 1024) {
        const int d = dst[e];
        const int s = src[e];
        const int b = d / BUCKET_W;
        const int pos = atomicAdd(&lcur[b], 1);         // LDS atomic
        part[pos] = (s << 9) | (d - b * BUCKET_W);
    }
}

// ---------------- pass C: counting sort (parallel scan) + fused convert_scale ----------
__global__ __launch_bounds__(512) void bucket_csr(const int* __restrict__ cursor,
                                                  const int* __restrict__ part,
                                                  const float* __restrict__ feature,
                                                  int* __restrict__ col,
                                                  int2* __restrict__ rows,
                                                  float* __restrict__ dinv,
                                                  __half* __restrict__ xh) {
    __shared__ int ed[CCAP];
    __shared__ int hist[BUCKET_W];
    __shared__ int lcur[BUCKET_W];
    __shared__ int sc[512];
    const int b = blockIdx.x;
    const int base = b * CCAP;
    const int cnt = min(cursor[b * 16], CCAP);
    const int n0 = b * BUCKET_W;
    const int nn = min(N_NODES - n0, BUCKET_W);
    const int t = threadIdx.x;

    if (t < BUCKET_W) hist[t] = 0;
    for (int i = t; i < cnt; i += 512) ed[i] = part[base + i];
    __syncthreads();
    for (int i = t; i < cnt; i += 512) atomicAdd(&hist[ed[i] & LMASK], 1);
    __syncthreads();
    // parallel exclusive scan of hist[0..nn) (nn <= 391 < 512)
    const int v = (t < nn) ? hist[t] : 0;
    sc[t] = v;
    __syncthreads();
    for (int off = 1; off < 512; off <<= 1) {
        int u = (t >= off) ? sc[t - off] : 0;
        __syncthreads();
        sc[t] += u;
        __syncthreads();
    }
    if (t < nn) {
        const int excl = sc[t] - v;
        lcur[t] = base + excl;
        rows[n0 + t] = make_int2(base + excl, base + excl + v);
        dinv[n0 + t] = rsqrtf((float)v + 1.0f);
    }
    __syncthreads();
    for (int i = t; i < cnt; i += 512) {
        const int p = ed[i];
        const int pos = atomicAdd(&lcur[p & LMASK], 1);
        col[pos] = p >> 9;
    }
    // fused convert_scale for this bucket's nodes: xh[n] = (half)(x[n]*dinv[n])
    const float2* f2 = (const float2*)feature;
    __half2* x2 = (__half2*)xh;
    for (int i = t; i < nn * 32; i += 512) {
        const int node = i >> 5, idx = i & 31;
        const float dv = rsqrtf((float)hist[node] + 1.0f);
        const float2 u = f2[(size_t)(n0 + node) * 32 + idx];
        x2[(size_t)(n0 + node) * 32 + idx] = __floats2half2_rn(u.x * dv, u.y * dv);
    }
}

// ---------------- aggregation, 2 nodes per wave (interleaved gather streams) -----------
__device__ __forceinline__ int rlane_i(int v, int l) {
    return __builtin_amdgcn_readlane(v, l);
}

#define GATHER4(acc0, acc1, acc2, acc3, creg, tt)                         \
    {                                                                     \
        const int s0 = rlane_i(creg, tt + 0), s1 = rlane_i(creg, tt + 1); \
        const int s2 = rlane_i(creg, tt + 2), s3 = rlane_i(creg, tt + 3); \
        acc0 += __half2float(xh[(size_t)s0 * D + lane]);                  \
        acc1 += __half2float(xh[(size_t)s1 * D + lane]);                  \
        acc2 += __half2float(xh[(size_t)s2 * D + lane]);                  \
        acc3 += __half2float(xh[(size_t)s3 * D + lane]);                  \
    }

__global__ __launch_bounds__(256) void agg_pair(const __half* __restrict__ xh,
                                                const int2* __restrict__ rows,
                                                const int* __restrict__ col,
                                                const float* __restrict__ dinv,
                                                __half* __restrict__ aggh, int n) {
    const int gwave = (blockIdx.x * blockDim.x + threadIdx.x) >> 6;
    const int lane = threadIdx.x & 63;
    const int nd0 = gwave * 2;
    if (nd0 >= n) return;
    const int nd1 = nd0 + 1;          // n is even: always valid

    const int2 r0 = rows[nd0];
    const int2 r1 = rows[nd1];
    const int b0 = r0.x, e0 = r0.y;
    const int b1 = r1.x, e1 = r1.y;

    const int ch0 = min(e0 - b0, 64);
    const int ch1 = min(e1 - b1, 64);
    const int c0 = (lane < ch0) ? col[b0 + lane] : 0;   // both chunks in flight
    const int c1 = (lane < ch1) ? col[b1 + lane] : 0;

    float a0 = 0.f, a1 = 0.f, a2 = 0.f, a3 = 0.f;   // node0
    float d0 = 0.f, d1 = 0.f, d2 = 0.f, d3 = 0.f;   // node1

    const int m = min(ch0, ch1) & ~3;
    int t = 0;
    for (; t < m; t += 4) {                 // interleaved: 8 independent gathers in flight
        GATHER4(a0, a1, a2, a3, c0, t)
        GATHER4(d0, d1, d2, d3, c1, t)
    }
    int t0 = t, t1 = t;
    for (; t0 + 3 < ch0; t0 += 4) GATHER4(a0, a1, a2, a3, c0, t0)
    for (; t0 < ch0; ++t0) a0 += __half2float(xh[(size_t)rlane_i(c0, t0) * D + lane]);
    for (; t1 + 3 < ch1; t1 += 4) GATHER4(d0, d1, d2, d3, c1, t1)
    for (; t1 < ch1; ++t1) d0 += __half2float(xh[(size_t)rlane_i(c1, t1) * D + lane]);

    // residual chunks for degree > 64 (essentially never for Poisson(16); kept for safety)
    for (int j = b0 + 64; j < e0; j += 64) {
        const int chunk = min(e0 - j, 64);
        const int c = (lane < chunk) ? col[j + lane] : 0;
        int tt = 0;
        for (; tt + 3 < chunk; tt += 4) GATHER4(a0, a1, a2, a3, c, tt)
        for (; tt < chunk; ++tt) a0 += __half2float(xh[(size_t)rlane_i(c, tt) * D + lane]);
    }
    for (int j = b1 + 64; j < e1; j += 64) {
        const int chunk = min(e1 - j, 64);
        const int c = (lane < chunk) ? col[j + lane] : 0;
        int tt = 0;
        for (; tt + 3 < chunk; tt += 4) GATHER4(d0, d1, d2, d3, c, tt)
        for (; tt < chunk; ++tt) d0 += __half2float(xh[(size_t)rlane_i(c, tt) * D + lane]);
    }

    const float self0 = __half2float(xh[(size_t)nd0 * D + lane]);
    aggh[(size_t)nd0 * D + lane] =
        __float2half(dinv[nd0] * ((a0 + a1) + (a2 + a3) + self0));
    const float self1 = __half2float(xh[(size_t)nd1 * D + lane]);
    aggh[(size_t)nd1 * D + lane] =
        __float2half(dinv[nd1] * ((d0 + d1) + (d2 + d3) + self1));
}

// ---------------- GEMM: r = relu(agg @ W + b); write fp32 or scaled-fp16 ----------------
__device__ __forceinline__ float rlane_ff(float v, int l) {
    return __int_as_float(__builtin_amdgcn_readlane(__float_as_int(v), l));
}

template <bool SCALED_HALF_OUT>
__global__ __launch_bounds__(256) void gemm64(const __half* __restrict__ aggh,
                                              const float* __restrict__ W,
                                              const float* __restrict__ bias,
                                              const float* __restrict__ dinv,
                                              float* __restrict__ out,
                                              __half* __restrict__ outh, int n) {
    const int lane = threadIdx.x & 63;
    const int gwave = (blockIdx.x * blockDim.x + threadIdx.x) >> 6;
    const int nwaves = (gridDim.x * blockDim.x) >> 6;
    float wcol[64];
#pragma unroll
    for (int k = 0; k < 64; ++k) wcol[k] = W[k * 64 + lane];
    const float bv = bias[lane];

    for (int nd = gwave; nd < n; nd += nwaves) {
        const float a = __half2float(aggh[(size_t)nd * D + lane]);
        float g0 = 0.f, g1 = 0.f, g2 = 0.f, g3 = 0.f;
#pragma unroll
        for (int k = 0; k < 64; k += 4) {
            g0 = fmaf(rlane_ff(a, k + 0), wcol[k + 0], g0);
            g1 = fmaf(rlane_ff(a, k + 1), wcol[k + 1], g1);
            g2 = fmaf(rlane_ff(a, k + 2), wcol[k + 2], g2);
            g3 = fmaf(rlane_ff(a, k + 3), wcol[k + 3], g3);
        }
        const float r = fmaxf((g0 + g1) + (g2 + g3) + bv, 0.f);
        if (SCALED_HALF_OUT)
            outh[(size_t)nd * D + lane] = __float2half(r * dinv[nd]);
        else
            out[(size_t)nd * D + lane] = r;
    }
}

extern "C" void kernel_launch(void* const* d_in, const int* in_sizes, int n_in,
                              void* d_out, int out_size, void* d_ws, size_t ws_size,
                              hipStream_t stream) {
    const float* feature = (const float*)d_in[0];
    const int*   edges   = (const int*)d_in[1];   // [2, E] flat: src then dst
    const float* W1      = (const float*)d_in[2];
    const float* b1      = (const float*)d_in[3];
    const float* W2      = (const float*)d_in[4];
    const float* b2      = (const float*)d_in[5];
    float* out = (float*)d_out;

    const int* src = edges;
    const int* dst = edges + N_EDGES;

    // workspace layout (~55MB)
    char* w = (char*)d_ws;
    int*    cursor = (int*)w;    w += sizeof(int) * (NB * 16);            // padded counters
    int2*   rows   = (int2*)w;   w += sizeof(int2) * (N_NODES);           // 800KB
    float*  dinv   = (float*)w;  w += sizeof(float) * (N_NODES);
    int*    part   = (int*)w;    w += sizeof(int) * (NB * CCAP);          // 7.3MB
    int*    colA   = (int*)w;    w += sizeof(int) * (NB * CCAP);          // 7.3MB
    __half* xh     = (__half*)w; w += sizeof(__half) * ((size_t)N_NODES * D);  // 12.8MB
    __half* y1h    = (__half*)w; w += sizeof(__half) * ((size_t)N_NODES * D);  // 12.8MB
    __half* aggh   = (__half*)w; w += sizeof(__half) * ((size_t)N_NODES * D);  // 12.8MB

    // ---- front-end: reserve+partition, then sort+convert (once) ----
    hipMemsetAsync(cursor, 0, sizeof(int) * NB * 16, stream);
    partition_fused<<<NBLK, 1024, 0, stream>>>(src, dst, cursor, part);
    bucket_csr<<<NB_USED, 512, 0, stream>>>(cursor, part, feature, colA, rows, dinv, xh);

    const int pair_blocks = (N_NODES / 2 + 3) / 4;   // 2 nodes/wave, 4 waves/block

    // ---- layer 1 ----
    agg_pair<<<pair_blocks, 256, 0, stream>>>(xh, rows, colA, dinv, aggh, N_NODES);
    gemm64<true><<<2048, 256, 0, stream>>>(aggh, W1, b1, dinv, nullptr, y1h, N_NODES);

    // ---- layer 2 ----
    agg_pair<<<pair_blocks, 256, 0, stream>>>(y1h, rows, colA, dinv, aggh, N_NODES);
    gemm64<false><<<2048, 256, 0, stream>>>(aggh, W2, b2, dinv, out, nullptr, N_NODES);
}

// Round 18
// 173.952 us; speedup vs baseline: 1.3623x; 1.0221x over previous
//
#include <hip/hip_runtime.h>
#include <hip/hip_fp16.h>

#define N_NODES 100000
#define N_EDGES 1600000
#define D 64

#define NB 256                  // fat buckets
#define BUCKET_W 391            // nodes per bucket (256*391 = 100096 >= 100000)
#define NB_USED 256
#define NBLK 256                // partition blocks
#define CHUNK ((N_EDGES + NBLK - 1) / NBLK)             // 6250
#define CCAP 7168               // fixed bucket capacity (mean 6250, sd ~79 -> 11 sigma)
#define LMASK 511               // 9-bit local node index

// ---------------- fused count+reserve+scatter: one pass, no scan kernel ----------------
__global__ __launch_bounds__(1024) void partition_fused(const int* __restrict__ src,
                                                        const int* __restrict__ dst,
                                                        int* __restrict__ cursor,
                                                        int* __restrict__ part) {
    __shared__ int h[NB];
    __shared__ int lcur[NB];
    const int t = threadIdx.x;
    if (t < NB) h[t] = 0;
    __syncthreads();
    const int blk = blockIdx.x;
    const int beg = blk * CHUNK;
    const int end = min(beg + CHUNK, N_EDGES);
    for (int e = beg + t; e < end; e += 1024)
        atomicAdd(&h[dst[e] / BUCKET_W], 1);
    __syncthreads();
    if (t < NB) {
        const int c = h[t];
        const int base = c ? atomicAdd(&cursor[t * 16], c) : 0;   // padded counter line
        lcur[t] = t * CCAP + base;
    }
    __syncthreads();
    for (int e = beg + t; e < end; e += 1024) {
        const int d = dst[e];
        const int s = src[e];
        const int b = d / BUCKET_W;
        const int pos = atomicAdd(&lcur[b], 1);         // LDS atomic
        part[pos] = (s << 9) | (d - b * BUCKET_W);
    }
}

// ---------------- pass C: counting sort (parallel scan) + fused convert_scale ----------
__global__ __launch_bounds__(512) void bucket_csr(const int* __restrict__ cursor,
                                                  const int* __restrict__ part,
                                                  const float* __restrict__ feature,
                                                  int* __restrict__ col,
                                                  int2* __restrict__ rows,
                                                  float* __restrict__ dinv,
                                                  __half* __restrict__ xh) {
    __shared__ int ed[CCAP];
    __shared__ int hist[BUCKET_W];
    __shared__ int lcur[BUCKET_W];
    __shared__ int sc[512];
    const int b = blockIdx.x;
    const int base = b * CCAP;
    const int cnt = min(cursor[b * 16], CCAP);
    const int n0 = b * BUCKET_W;
    const int nn = min(N_NODES - n0, BUCKET_W);
    const int t = threadIdx.x;

    if (t < BUCKET_W) hist[t] = 0;
    for (int i = t; i < cnt; i += 512) ed[i] = part[base + i];
    __syncthreads();
    for (int i = t; i < cnt; i += 512) atomicAdd(&hist[ed[i] & LMASK], 1);
    __syncthreads();
    // parallel exclusive scan of hist[0..nn) (nn <= 391 < 512)
    const int v = (t < nn) ? hist[t] : 0;
    sc[t] = v;
    __syncthreads();
    for (int off = 1; off < 512; off <<= 1) {
        int u = (t >= off) ? sc[t - off] : 0;
        __syncthreads();
        sc[t] += u;
        __syncthreads();
    }
    if (t < nn) {
        const int excl = sc[t] - v;
        lcur[t] = base + excl;
        rows[n0 + t] = make_int2(base + excl, base + excl + v);
        dinv[n0 + t] = rsqrtf((float)v + 1.0f);
    }
    __syncthreads();
    for (int i = t; i < cnt; i += 512) {
        const int p = ed[i];
        const int pos = atomicAdd(&lcur[p & LMASK], 1);
        col[pos] = p >> 9;
    }
    // fused convert_scale for this bucket's nodes: xh[n] = (half)(x[n]*dinv[n])
    const float2* f2p = (const float2*)feature;
    __half2* x2 = (__half2*)xh;
    for (int i = t; i < nn * 32; i += 512) {
        const int node = i >> 5, idx = i & 31;
        const float dv = rsqrtf((float)hist[node] + 1.0f);
        const float2 u = f2p[(size_t)(n0 + node) * 32 + idx];
        x2[(size_t)(n0 + node) * 32 + idx] = __floats2half2_rn(u.x * dv, u.y * dv);
    }
}

// ---------------- aggregation: 2 nodes/wave, half2 lane-split gathers ------------------
// Wave = (node pair); lanes = (hsel = edge parity half, f2 = feature pair 0..31).
// One 4B half2 load covers 2 features x (2 edges per instruction across halves):
// memory-instruction count per edge halved vs 2B-per-lane gathers. Layout of xh/aggh
// rows is unchanged (linear fp16), so gemm64 and the front-end are untouched.
__device__ __forceinline__ int rlane_i(int v, int l) {
    return __builtin_amdgcn_readlane(v, l);
}

// edges 2*tt .. 2*tt+7 of one node (8 edges, 4 half2 loads per lane)
#define GPAIR4(accA, accB, accC, accD, creg, tt)                                   \
    {                                                                              \
        const int sa0 = rlane_i(creg, 2 * (tt) + 0), sb0 = rlane_i(creg, 2 * (tt) + 1); \
        const int sa1 = rlane_i(creg, 2 * (tt) + 2), sb1 = rlane_i(creg, 2 * (tt) + 3); \
        const int sa2 = rlane_i(creg, 2 * (tt) + 4), sb2 = rlane_i(creg, 2 * (tt) + 5); \
        const int sa3 = rlane_i(creg, 2 * (tt) + 6), sb3 = rlane_i(creg, 2 * (tt) + 7); \
        const int s0 = hsel ? sb0 : sa0;                                           \
        const int s1 = hsel ? sb1 : sa1;                                           \
        const int s2 = hsel ? sb2 : sa2;                                           \
        const int s3 = hsel ? sb3 : sa3;                                           \
        const float2 v0 = __half22float2(xh2[(size_t)s0 * 32 + f2]);               \
        const float2 v1 = __half22float2(xh2[(size_t)s1 * 32 + f2]);               \
        const float2 v2 = __half22float2(xh2[(size_t)s2 * 32 + f2]);               \
        const float2 v3 = __half22float2(xh2[(size_t)s3 * 32 + f2]);               \
        accA.x += v0.x; accA.y += v0.y;                                            \
        accB.x += v1.x; accB.y += v1.y;                                            \
        accC.x += v2.x; accC.y += v2.y;                                            \
        accD.x += v3.x; accD.y += v3.y;                                            \
    }

// edges 2*tt, 2*tt+1 (one load)
#define GPAIR1(accA, creg, tt)                                                     \
    {                                                                              \
        const int sa = rlane_i(creg, 2 * (tt) + 0), sb = rlane_i(creg, 2 * (tt) + 1);   \
        const int s = hsel ? sb : sa;                                              \
        const float2 v = __half22float2(xh2[(size_t)s * 32 + f2]);                 \
        accA.x += v.x; accA.y += v.y;                                              \
    }

// last (odd) edge: halfA only
#define GODD(accA, creg, ch)                                                       \
    if ((ch) & 1) {                                                                \
        const int s = rlane_i(creg, (ch) - 1);                                     \
        if (!hsel) {                                                               \
            const float2 v = __half22float2(xh2[(size_t)s * 32 + f2]);             \
            accA.x += v.x; accA.y += v.y;                                          \
        }                                                                          \
    }

__global__ __launch_bounds__(256) void agg_pair(const __half* __restrict__ xh,
                                                const int2* __restrict__ rows,
                                                const int* __restrict__ col,
                                                const float* __restrict__ dinv,
                                                __half* __restrict__ aggh, int n) {
    const int gwave = (blockIdx.x * blockDim.x + threadIdx.x) >> 6;
    const int lane = threadIdx.x & 63;
    const int nd0 = gwave * 2;
    if (nd0 >= n) return;
    const int nd1 = nd0 + 1;          // n is even
    const int f2 = lane & 31;
    const int hsel = lane >> 5;
    const __half2* xh2 = (const __half2*)xh;

    const int2 r0 = rows[nd0];
    const int2 r1 = rows[nd1];
    const int b0 = r0.x, e0 = r0.y;
    const int b1 = r1.x, e1 = r1.y;

    const int ch0 = min(e0 - b0, 64);
    const int ch1 = min(e1 - b1, 64);
    const int c0 = (lane < ch0) ? col[b0 + lane] : 0;   // both chunks in flight
    const int c1 = (lane < ch1) ? col[b1 + lane] : 0;

    float2 A0 = make_float2(0.f, 0.f), A1 = make_float2(0.f, 0.f);
    float2 A2 = make_float2(0.f, 0.f), A3 = make_float2(0.f, 0.f);
    float2 B0 = make_float2(0.f, 0.f), B1 = make_float2(0.f, 0.f);
    float2 B2 = make_float2(0.f, 0.f), B3 = make_float2(0.f, 0.f);

    const int np0 = ch0 >> 1, np1 = ch1 >> 1;
    const int mm = min(np0, np1) & ~3;
    int t = 0;
    for (; t < mm; t += 4) {            // interleaved: 8 loads / 16 edges in flight
        GPAIR4(A0, A1, A2, A3, c0, t)
        GPAIR4(B0, B1, B2, B3, c1, t)
    }
    int t0 = t, t1 = t;
    for (; t0 + 3 < np0; t0 += 4) GPAIR4(A0, A1, A2, A3, c0, t0)
    for (; t0 < np0; ++t0) GPAIR1(A0, c0, t0)
    GODD(A0, c0, ch0)
    for (; t1 + 3 < np1; t1 += 4) GPAIR4(B0, B1, B2, B3, c1, t1)
    for (; t1 < np1; ++t1) GPAIR1(B0, c1, t1)
    GODD(B0, c1, ch1)

    // residual chunks for degree > 64 (essentially never for Poisson(16))
    for (int j = b0 + 64; j < e0; j += 64) {
        const int chunk = min(e0 - j, 64);
        const int c = (lane < chunk) ? col[j + lane] : 0;
        const int np = chunk >> 1;
        int tt = 0;
        for (; tt + 3 < np; tt += 4) GPAIR4(A0, A1, A2, A3, c, tt)
        for (; tt < np; ++tt) GPAIR1(A0, c, tt)
        GODD(A0, c, chunk)
    }
    for (int j = b1 + 64; j < e1; j += 64) {
        const int chunk = min(e1 - j, 64);
        const int c = (lane < chunk) ? col[j + lane] : 0;
        const int np = chunk >> 1;
        int tt = 0;
        for (; tt + 3 < np; tt += 4) GPAIR4(B0, B1, B2, B3, c, tt)
        for (; tt < np; ++tt) GPAIR1(B0, c, tt)
        GODD(B0, c, chunk)
    }

    float2 sA, sB;
    sA.x = (A0.x + A1.x) + (A2.x + A3.x);
    sA.y = (A0.y + A1.y) + (A2.y + A3.y);
    sB.x = (B0.x + B1.x) + (B2.x + B3.x);
    sB.y = (B0.y + B1.y) + (B2.y + B3.y);
    sA.x += __shfl_xor(sA.x, 32, 64);   // combine edge-parity halves
    sA.y += __shfl_xor(sA.y, 32, 64);
    sB.x += __shfl_xor(sB.x, 32, 64);
    sB.y += __shfl_xor(sB.y, 32, 64);

    if (!hsel) {                        // lanes 0..31 write the 128B rows
        __half2* aggh2 = (__half2*)aggh;
        const float dv0 = dinv[nd0], dv1 = dinv[nd1];
        const float2 self0 = __half22float2(xh2[(size_t)nd0 * 32 + f2]);
        const float2 self1 = __half22float2(xh2[(size_t)nd1 * 32 + f2]);
        aggh2[(size_t)nd0 * 32 + f2] =
            __floats2half2_rn(dv0 * (sA.x + self0.x), dv0 * (sA.y + self0.y));
        aggh2[(size_t)nd1 * 32 + f2] =
            __floats2half2_rn(dv1 * (sB.x + self1.x), dv1 * (sB.y + self1.y));
    }
}

// ---------------- GEMM: r = relu(agg @ W + b); write fp32 or scaled-fp16 ----------------
__device__ __forceinline__ float rlane_ff(float v, int l) {
    return __int_as_float(__builtin_amdgcn_readlane(__float_as_int(v), l));
}

template <bool SCALED_HALF_OUT>
__global__ __launch_bounds__(256) void gemm64(const __half* __restrict__ aggh,
                                              const float* __restrict__ W,
                                              const float* __restrict__ bias,
                                              const float* __restrict__ dinv,
                                              float* __restrict__ out,
                                              __half* __restrict__ outh, int n) {
    const int lane = threadIdx.x & 63;
    const int gwave = (blockIdx.x * blockDim.x + threadIdx.x) >> 6;
    const int nwaves = (gridDim.x * blockDim.x) >> 6;
    float wcol[64];
#pragma unroll
    for (int k = 0; k < 64; ++k) wcol[k] = W[k * 64 + lane];
    const float bv = bias[lane];

    for (int nd = gwave; nd < n; nd += nwaves) {
        const float a = __half2float(aggh[(size_t)nd * D + lane]);
        float g0 = 0.f, g1 = 0.f, g2 = 0.f, g3 = 0.f;
#pragma unroll
        for (int k = 0; k < 64; k += 4) {
            g0 = fmaf(rlane_ff(a, k + 0), wcol[k + 0], g0);
            g1 = fmaf(rlane_ff(a, k + 1), wcol[k + 1], g1);
            g2 = fmaf(rlane_ff(a, k + 2), wcol[k + 2], g2);
            g3 = fmaf(rlane_ff(a, k + 3), wcol[k + 3], g3);
        }
        const float r = fmaxf((g0 + g1) + (g2 + g3) + bv, 0.f);
        if (SCALED_HALF_OUT)
            outh[(size_t)nd * D + lane] = __float2half(r * dinv[nd]);
        else
            out[(size_t)nd * D + lane] = r;
    }
}

extern "C" void kernel_launch(void* const* d_in, const int* in_sizes, int n_in,
                              void* d_out, int out_size, void* d_ws, size_t ws_size,
                              hipStream_t stream) {
    const float* feature = (const float*)d_in[0];
    const int*   edges   = (const int*)d_in[1];   // [2, E] flat: src then dst
    const float* W1      = (const float*)d_in[2];
    const float* b1      = (const float*)d_in[3];
    const float* W2      = (const float*)d_in[4];
    const float* b2      = (const float*)d_in[5];
    float* out = (float*)d_out;

    const int* src = edges;
    const int* dst = edges + N_EDGES;

    // workspace layout (~55MB)
    char* w = (char*)d_ws;
    int*    cursor = (int*)w;    w += sizeof(int) * (NB * 16);            // padded counters
    int2*   rows   = (int2*)w;   w += sizeof(int2) * (N_NODES);           // 800KB
    float*  dinv   = (float*)w;  w += sizeof(float) * (N_NODES);
    int*    part   = (int*)w;    w += sizeof(int) * (NB * CCAP);          // 7.3MB
    int*    colA   = (int*)w;    w += sizeof(int) * (NB * CCAP);          // 7.3MB
    __half* xh     = (__half*)w; w += sizeof(__half) * ((size_t)N_NODES * D);  // 12.8MB
    __half* y1h    = (__half*)w; w += sizeof(__half) * ((size_t)N_NODES * D);  // 12.8MB
    __half* aggh   = (__half*)w; w += sizeof(__half) * ((size_t)N_NODES * D);  // 12.8MB

    // ---- front-end: reserve+partition, then sort+convert (once) ----
    hipMemsetAsync(cursor, 0, sizeof(int) * NB * 16, stream);
    partition_fused<<<NBLK, 1024, 0, stream>>>(src, dst, cursor, part);
    bucket_csr<<<NB_USED, 512, 0, stream>>>(cursor, part, feature, colA, rows, dinv, xh);

    const int pair_blocks = (N_NODES / 2 + 3) / 4;   // 2 nodes/wave, 4 waves/block

    // ---- layer 1 ----
    agg_pair<<<pair_blocks, 256, 0, stream>>>(xh, rows, colA, dinv, aggh, N_NODES);
    gemm64<true><<<2048, 256, 0, stream>>>(aggh, W1, b1, dinv, nullptr, y1h, N_NODES);

    // ---- layer 2 ----
    agg_pair<<<pair_blocks, 256, 0, stream>>>(y1h, rows, colA, dinv, aggh, N_NODES);
    gemm64<false><<<2048, 256, 0, stream>>>(aggh, W2, b2, dinv, out, nullptr, N_NODES);
}

// Round 19
// 168.189 us; speedup vs baseline: 1.4089x; 1.0343x over previous
//
#include <hip/hip_runtime.h>
#include <hip/hip_fp16.h>

#define N_NODES 100000
#define N_EDGES 1600000
#define D 64

#define NB 256                  // fat buckets
#define BUCKET_W 391            // nodes per bucket (256*391 = 100096 >= 100000)
#define NB_USED 256
#define NBLK 256                // partition blocks
#define CHUNK ((N_EDGES + NBLK - 1) / NBLK)             // 6250
#define CCAP 7168               // fixed bucket capacity (mean 6250, sd ~79 -> 11 sigma)
#define LMASK 511               // 9-bit local node index

// ---------------- fused count+reserve+scatter: one pass, no scan kernel ----------------
__global__ __launch_bounds__(1024) void partition_fused(const int* __restrict__ src,
                                                        const int* __restrict__ dst,
                                                        int* __restrict__ cursor,
                                                        int* __restrict__ part) {
    __shared__ int h[NB];
    __shared__ int lcur[NB];
    const int t = threadIdx.x;
    if (t < NB) h[t] = 0;
    __syncthreads();
    const int blk = blockIdx.x;
    const int beg = blk * CHUNK;
    const int end = min(beg + CHUNK, N_EDGES);
    for (int e = beg + t; e < end; e += 1024)
        atomicAdd(&h[dst[e] / BUCKET_W], 1);
    __syncthreads();
    if (t < NB) {
        const int c = h[t];
        const int base = c ? atomicAdd(&cursor[t * 16], c) : 0;   // padded counter line
        lcur[t] = t * CCAP + base;
    }
    __syncthreads();
    for (int e = beg + t; e < end; e += 1024) {
        const int d = dst[e];
        const int s = src[e];
        const int b = d / BUCKET_W;
        const int pos = atomicAdd(&lcur[b], 1);         // LDS atomic
        part[pos] = (s << 9) | (d - b * BUCKET_W);
    }
}

// ---------------- pass C: counting sort (parallel scan) -> col, rows, dinv -------------
__global__ __launch_bounds__(512) void bucket_csr(const int* __restrict__ cursor,
                                                  const int* __restrict__ part,
                                                  int* __restrict__ col,
                                                  int2* __restrict__ rows,
                                                  float* __restrict__ dinv) {
    __shared__ int ed[CCAP];
    __shared__ int hist[BUCKET_W];
    __shared__ int lcur[BUCKET_W];
    __shared__ int sc[512];
    const int b = blockIdx.x;
    const int base = b * CCAP;
    const int cnt = min(cursor[b * 16], CCAP);
    const int n0 = b * BUCKET_W;
    const int nn = min(N_NODES - n0, BUCKET_W);
    const int t = threadIdx.x;

    if (t < BUCKET_W) hist[t] = 0;
    for (int i = t; i < cnt; i += 512) ed[i] = part[base + i];
    __syncthreads();
    for (int i = t; i < cnt; i += 512) atomicAdd(&hist[ed[i] & LMASK], 1);
    __syncthreads();
    // parallel exclusive scan of hist[0..nn) (nn <= 391 < 512)
    const int v = (t < nn) ? hist[t] : 0;
    sc[t] = v;
    __syncthreads();
    for (int off = 1; off < 512; off <<= 1) {
        int u = (t >= off) ? sc[t - off] : 0;
        __syncthreads();
        sc[t] += u;
        __syncthreads();
    }
    if (t < nn) {
        const int excl = sc[t] - v;
        lcur[t] = base + excl;
        rows[n0 + t] = make_int2(base + excl, base + excl + v);
        dinv[n0 + t] = rsqrtf((float)v + 1.0f);
    }
    __syncthreads();
    for (int i = t; i < cnt; i += 512) {
        const int p = ed[i];
        const int pos = atomicAdd(&lcur[p & LMASK], 1);
        col[pos] = p >> 9;
    }
}

// ---------------- gemm_pre: hsc[nd] = dinv[nd] * (x[nd] @ W)  [fp16 out] ----------------
// W applied FIRST (A_hat(XW) == (A_hat X)W): aggregation then writes the final layer
// output directly, eliminating the agg round-trip buffer.
__device__ __forceinline__ float rlane_ff(float v, int l) {
    return __int_as_float(__builtin_amdgcn_readlane(__float_as_int(v), l));
}

template <bool IN_HALF>
__global__ __launch_bounds__(256) void gemm_pre(const void* __restrict__ xin,
                                                const float* __restrict__ W,
                                                const float* __restrict__ dinv,
                                                __half* __restrict__ hsc, int n) {
    const int lane = threadIdx.x & 63;
    const int gwave = (blockIdx.x * blockDim.x + threadIdx.x) >> 6;
    const int nwaves = (gridDim.x * blockDim.x) >> 6;
    float wcol[64];
#pragma unroll
    for (int k = 0; k < 64; ++k) wcol[k] = W[k * 64 + lane];

    for (int nd = gwave; nd < n; nd += nwaves) {
        float a;
        if (IN_HALF) a = __half2float(((const __half*)xin)[(size_t)nd * D + lane]);
        else         a = ((const float*)xin)[(size_t)nd * D + lane];
        float g0 = 0.f, g1 = 0.f, g2 = 0.f, g3 = 0.f;
#pragma unroll
        for (int k = 0; k < 64; k += 4) {
            g0 = fmaf(rlane_ff(a, k + 0), wcol[k + 0], g0);
            g1 = fmaf(rlane_ff(a, k + 1), wcol[k + 1], g1);
            g2 = fmaf(rlane_ff(a, k + 2), wcol[k + 2], g2);
            g3 = fmaf(rlane_ff(a, k + 3), wcol[k + 3], g3);
        }
        hsc[(size_t)nd * D + lane] = __float2half(((g0 + g1) + (g2 + g3)) * dinv[nd]);
    }
}

// ---------------- aggregation + epilogue: out = relu(dv*(sum hsc + hsc_self) + b) ------
// 2 nodes/wave, half2 lane-split gathers (R17 structure). Epilogue fused in registers.
__device__ __forceinline__ int rlane_i(int v, int l) {
    return __builtin_amdgcn_readlane(v, l);
}

#define GPAIR4(accA, accB, accC, accD, creg, tt)                                   \
    {                                                                              \
        const int sa0 = rlane_i(creg, 2 * (tt) + 0), sb0 = rlane_i(creg, 2 * (tt) + 1); \
        const int sa1 = rlane_i(creg, 2 * (tt) + 2), sb1 = rlane_i(creg, 2 * (tt) + 3); \
        const int sa2 = rlane_i(creg, 2 * (tt) + 4), sb2 = rlane_i(creg, 2 * (tt) + 5); \
        const int sa3 = rlane_i(creg, 2 * (tt) + 6), sb3 = rlane_i(creg, 2 * (tt) + 7); \
        const int s0 = hsel ? sb0 : sa0;                                           \
        const int s1 = hsel ? sb1 : sa1;                                           \
        const int s2 = hsel ? sb2 : sa2;                                           \
        const int s3 = hsel ? sb3 : sa3;                                           \
        const float2 v0 = __half22float2(xh2[(size_t)s0 * 32 + f2]);               \
        const float2 v1 = __half22float2(xh2[(size_t)s1 * 32 + f2]);               \
        const float2 v2 = __half22float2(xh2[(size_t)s2 * 32 + f2]);               \
        const float2 v3 = __half22float2(xh2[(size_t)s3 * 32 + f2]);               \
        accA.x += v0.x; accA.y += v0.y;                                            \
        accB.x += v1.x; accB.y += v1.y;                                            \
        accC.x += v2.x; accC.y += v2.y;                                            \
        accD.x += v3.x; accD.y += v3.y;                                            \
    }

#define GPAIR1(accA, creg, tt)                                                     \
    {                                                                              \
        const int sa = rlane_i(creg, 2 * (tt) + 0), sb = rlane_i(creg, 2 * (tt) + 1);   \
        const int s = hsel ? sb : sa;                                              \
        const float2 v = __half22float2(xh2[(size_t)s * 32 + f2]);                 \
        accA.x += v.x; accA.y += v.y;                                              \
    }

#define GODD(accA, creg, ch)                                                       \
    if ((ch) & 1) {                                                                \
        const int s = rlane_i(creg, (ch) - 1);                                     \
        if (!hsel) {                                                               \
            const float2 v = __half22float2(xh2[(size_t)s * 32 + f2]);             \
            accA.x += v.x; accA.y += v.y;                                          \
        }                                                                          \
    }

template <bool FINAL>
__global__ __launch_bounds__(256) void agg_pair(const __half* __restrict__ hsc,
                                                const int2* __restrict__ rows,
                                                const int* __restrict__ col,
                                                const float* __restrict__ dinv,
                                                const float* __restrict__ bias,
                                                float* __restrict__ outf,
                                                __half* __restrict__ outh, int n) {
    const int gwave = (blockIdx.x * blockDim.x + threadIdx.x) >> 6;
    const int lane = threadIdx.x & 63;
    const int nd0 = gwave * 2;
    if (nd0 >= n) return;
    const int nd1 = nd0 + 1;          // n is even
    const int f2 = lane & 31;
    const int hsel = lane >> 5;
    const __half2* xh2 = (const __half2*)hsc;

    const int2 r0 = rows[nd0];
    const int2 r1 = rows[nd1];
    const int b0 = r0.x, e0 = r0.y;
    const int b1 = r1.x, e1 = r1.y;

    const int ch0 = min(e0 - b0, 64);
    const int ch1 = min(e1 - b1, 64);
    const int c0 = (lane < ch0) ? col[b0 + lane] : 0;   // both chunks in flight
    const int c1 = (lane < ch1) ? col[b1 + lane] : 0;

    float2 A0 = make_float2(0.f, 0.f), A1 = make_float2(0.f, 0.f);
    float2 A2 = make_float2(0.f, 0.f), A3 = make_float2(0.f, 0.f);
    float2 B0 = make_float2(0.f, 0.f), B1 = make_float2(0.f, 0.f);
    float2 B2 = make_float2(0.f, 0.f), B3 = make_float2(0.f, 0.f);

    const int np0 = ch0 >> 1, np1 = ch1 >> 1;
    const int mm = min(np0, np1) & ~3;
    int t = 0;
    for (; t < mm; t += 4) {            // interleaved: 8 loads / 16 edges in flight
        GPAIR4(A0, A1, A2, A3, c0, t)
        GPAIR4(B0, B1, B2, B3, c1, t)
    }
    int t0 = t, t1 = t;
    for (; t0 + 3 < np0; t0 += 4) GPAIR4(A0, A1, A2, A3, c0, t0)
    for (; t0 < np0; ++t0) GPAIR1(A0, c0, t0)
    GODD(A0, c0, ch0)
    for (; t1 + 3 < np1; t1 += 4) GPAIR4(B0, B1, B2, B3, c1, t1)
    for (; t1 < np1; ++t1) GPAIR1(B0, c1, t1)
    GODD(B0, c1, ch1)

    // residual chunks for degree > 64 (essentially never for Poisson(16))
    for (int j = b0 + 64; j < e0; j += 64) {
        const int chunk = min(e0 - j, 64);
        const int c = (lane < chunk) ? col[j + lane] : 0;
        const int np = chunk >> 1;
        int tt = 0;
        for (; tt + 3 < np; tt += 4) GPAIR4(A0, A1, A2, A3, c, tt)
        for (; tt < np; ++tt) GPAIR1(A0, c, tt)
        GODD(A0, c, chunk)
    }
    for (int j = b1 + 64; j < e1; j += 64) {
        const int chunk = min(e1 - j, 64);
        const int c = (lane < chunk) ? col[j + lane] : 0;
        const int np = chunk >> 1;
        int tt = 0;
        for (; tt + 3 < np; tt += 4) GPAIR4(B0, B1, B2, B3, c, tt)
        for (; tt < np; ++tt) GPAIR1(B0, c, tt)
        GODD(B0, c, chunk)
    }

    float2 sA, sB;
    sA.x = (A0.x + A1.x) + (A2.x + A3.x);
    sA.y = (A0.y + A1.y) + (A2.y + A3.y);
    sB.x = (B0.x + B1.x) + (B2.x + B3.x);
    sB.y = (B0.y + B1.y) + (B2.y + B3.y);
    sA.x += __shfl_xor(sA.x, 32, 64);   // combine edge-parity halves
    sA.y += __shfl_xor(sA.y, 32, 64);
    sB.x += __shfl_xor(sB.x, 32, 64);
    sB.y += __shfl_xor(sB.y, 32, 64);

    if (!hsel) {                        // lanes 0..31 write the rows
        const float dv0 = dinv[nd0], dv1 = dinv[nd1];
        const float2 self0 = __half22float2(xh2[(size_t)nd0 * 32 + f2]);
        const float2 self1 = __half22float2(xh2[(size_t)nd1 * 32 + f2]);
        const float2 bv = *(const float2*)(bias + f2 * 2);
        const float r0x = fmaxf(fmaf(dv0, sA.x + self0.x, bv.x), 0.f);
        const float r0y = fmaxf(fmaf(dv0, sA.y + self0.y, bv.y), 0.f);
        const float r1x = fmaxf(fmaf(dv1, sB.x + self1.x, bv.x), 0.f);
        const float r1y = fmaxf(fmaf(dv1, sB.y + self1.y, bv.y), 0.f);
        if (FINAL) {
            float2* o2 = (float2*)outf;
            o2[(size_t)nd0 * 32 + f2] = make_float2(r0x, r0y);
            o2[(size_t)nd1 * 32 + f2] = make_float2(r1x, r1y);
        } else {
            __half2* o2 = (__half2*)outh;
            o2[(size_t)nd0 * 32 + f2] = __floats2half2_rn(r0x, r0y);
            o2[(size_t)nd1 * 32 + f2] = __floats2half2_rn(r1x, r1y);
        }
    }
}

extern "C" void kernel_launch(void* const* d_in, const int* in_sizes, int n_in,
                              void* d_out, int out_size, void* d_ws, size_t ws_size,
                              hipStream_t stream) {
    const float* feature = (const float*)d_in[0];
    const int*   edges   = (const int*)d_in[1];   // [2, E] flat: src then dst
    const float* W1      = (const float*)d_in[2];
    const float* b1      = (const float*)d_in[3];
    const float* W2      = (const float*)d_in[4];
    const float* b2      = (const float*)d_in[5];
    float* out = (float*)d_out;

    const int* src = edges;
    const int* dst = edges + N_EDGES;

    // workspace layout (~42MB)
    char* w = (char*)d_ws;
    int*    cursor = (int*)w;    w += sizeof(int) * (NB * 16);            // padded counters
    int2*   rows   = (int2*)w;   w += sizeof(int2) * (N_NODES);           // 800KB
    float*  dinv   = (float*)w;  w += sizeof(float) * (N_NODES);
    int*    part   = (int*)w;    w += sizeof(int) * (NB * CCAP);          // 7.3MB
    int*    colA   = (int*)w;    w += sizeof(int) * (NB * CCAP);          // 7.3MB
    __half* hsc    = (__half*)w; w += sizeof(__half) * ((size_t)N_NODES * D);  // 12.8MB
    __half* y1h    = (__half*)w; w += sizeof(__half) * ((size_t)N_NODES * D);  // 12.8MB

    // ---- front-end: reserve+partition, then sort (once) ----
    hipMemsetAsync(cursor, 0, sizeof(int) * NB * 16, stream);
    partition_fused<<<NBLK, 1024, 0, stream>>>(src, dst, cursor, part);
    bucket_csr<<<NB_USED, 512, 0, stream>>>(cursor, part, colA, rows, dinv);

    const int pair_blocks = (N_NODES / 2 + 3) / 4;   // 2 nodes/wave, 4 waves/block

    // ---- layer 1: hsc = dinv*(x@W1); y1 = relu(A_hat-sum + b1) ----
    gemm_pre<false><<<2048, 256, 0, stream>>>(feature, W1, dinv, hsc, N_NODES);
    agg_pair<false><<<pair_blocks, 256, 0, stream>>>(hsc, rows, colA, dinv, b1,
                                                     nullptr, y1h, N_NODES);

    // ---- layer 2: hsc = dinv*(y1@W2); out = relu(A_hat-sum + b2) ----
    gemm_pre<true><<<2048, 256, 0, stream>>>(y1h, W2, dinv, hsc, N_NODES);
    agg_pair<true><<<pair_blocks, 256, 0, stream>>>(hsc, rows, colA, dinv, b2,
                                                    out, nullptr, N_NODES);
}

// Round 20
// 167.656 us; speedup vs baseline: 1.4134x; 1.0032x over previous
//
#include <hip/hip_runtime.h>
#include <hip/hip_fp16.h>

#define N_NODES 100000
#define N_EDGES 1600000
#define D 64

#define NB 256                  // fat buckets
#define BUCKET_W 391            // nodes per bucket (256*391 = 100096 >= 100000)
#define NB_USED 256
#define NBLK 256                // partition blocks
#define CHUNK ((N_EDGES + NBLK - 1) / NBLK)             // 6250
#define CCAP 7168               // fixed bucket capacity (mean 6250, sd ~79 -> 11 sigma)
#define LMASK 511               // 9-bit local node index

// ---------------- zero the reservation cursors (4096 ints) ----------------
// NOTE: rocclr fillBufferAligned costs ~41us for this 16KB fill (R18 profile);
// a plain kernel does it in ~3us.
__global__ __launch_bounds__(1024) void zero_cursor(int* __restrict__ p) {
    p[blockIdx.x * 1024 + threadIdx.x] = 0;
}

// ---------------- fused count+reserve+scatter: one pass, no scan kernel ----------------
__global__ __launch_bounds__(1024) void partition_fused(const int* __restrict__ src,
                                                        const int* __restrict__ dst,
                                                        int* __restrict__ cursor,
                                                        int* __restrict__ part) {
    __shared__ int h[NB];
    __shared__ int lcur[NB];
    const int t = threadIdx.x;
    if (t < NB) h[t] = 0;
    __syncthreads();
    const int blk = blockIdx.x;
    const int beg = blk * CHUNK;
    const int end = min(beg + CHUNK, N_EDGES);
    for (int e = beg + t; e < end; e += 1024)
        atomicAdd(&h[dst[e] / BUCKET_W], 1);
    __syncthreads();
    if (t < NB) {
        const int c = h[t];
        const int base = c ? atomicAdd(&cursor[t * 16], c) : 0;   // padded counter line
        lcur[t] = t * CCAP + base;
    }
    __syncthreads();
    for (int e = beg + t; e < end; e += 1024) {
        const int d = dst[e];
        const int s = src[e];
        const int b = d / BUCKET_W;
        const int pos = atomicAdd(&lcur[b], 1);         // LDS atomic
        part[pos] = (s << 9) | (d - b * BUCKET_W);
    }
}

// ---------------- pass C: counting sort (parallel scan) -> col, rows, dinv -------------
__global__ __launch_bounds__(512) void bucket_csr(const int* __restrict__ cursor,
                                                  const int* __restrict__ part,
                                                  int* __restrict__ col,
                                                  int2* __restrict__ rows,
                                                  float* __restrict__ dinv) {
    __shared__ int ed[CCAP];
    __shared__ int hist[BUCKET_W];
    __shared__ int lcur[BUCKET_W];
    __shared__ int sc[512];
    const int b = blockIdx.x;
    const int base = b * CCAP;
    const int cnt = min(cursor[b * 16], CCAP);
    const int n0 = b * BUCKET_W;
    const int nn = min(N_NODES - n0, BUCKET_W);
    const int t = threadIdx.x;

    if (t < BUCKET_W) hist[t] = 0;
    for (int i = t; i < cnt; i += 512) ed[i] = part[base + i];
    __syncthreads();
    for (int i = t; i < cnt; i += 512) atomicAdd(&hist[ed[i] & LMASK], 1);
    __syncthreads();
    // parallel exclusive scan of hist[0..nn) (nn <= 391 < 512)
    const int v = (t < nn) ? hist[t] : 0;
    sc[t] = v;
    __syncthreads();
    for (int off = 1; off < 512; off <<= 1) {
        int u = (t >= off) ? sc[t - off] : 0;
        __syncthreads();
        sc[t] += u;
        __syncthreads();
    }
    if (t < nn) {
        const int excl = sc[t] - v;
        lcur[t] = base + excl;
        rows[n0 + t] = make_int2(base + excl, base + excl + v);
        dinv[n0 + t] = rsqrtf((float)v + 1.0f);
    }
    __syncthreads();
    for (int i = t; i < cnt; i += 512) {
        const int p = ed[i];
        const int pos = atomicAdd(&lcur[p & LMASK], 1);
        col[pos] = p >> 9;
    }
}

// ---------------- gemm_pre: hsc[nd] = dinv[nd] * (x[nd] @ W)  [fp16 out] ----------------
__device__ __forceinline__ float rlane_ff(float v, int l) {
    return __int_as_float(__builtin_amdgcn_readlane(__float_as_int(v), l));
}

template <bool IN_HALF>
__global__ __launch_bounds__(256) void gemm_pre(const void* __restrict__ xin,
                                                const float* __restrict__ W,
                                                const float* __restrict__ dinv,
                                                __half* __restrict__ hsc, int n) {
    const int lane = threadIdx.x & 63;
    const int gwave = (blockIdx.x * blockDim.x + threadIdx.x) >> 6;
    const int nwaves = (gridDim.x * blockDim.x) >> 6;
    float wcol[64];
#pragma unroll
    for (int k = 0; k < 64; ++k) wcol[k] = W[k * 64 + lane];

    for (int nd = gwave; nd < n; nd += nwaves) {
        float a;
        if (IN_HALF) a = __half2float(((const __half*)xin)[(size_t)nd * D + lane]);
        else         a = ((const float*)xin)[(size_t)nd * D + lane];
        float g0 = 0.f, g1 = 0.f, g2 = 0.f, g3 = 0.f;
#pragma unroll
        for (int k = 0; k < 64; k += 4) {
            g0 = fmaf(rlane_ff(a, k + 0), wcol[k + 0], g0);
            g1 = fmaf(rlane_ff(a, k + 1), wcol[k + 1], g1);
            g2 = fmaf(rlane_ff(a, k + 2), wcol[k + 2], g2);
            g3 = fmaf(rlane_ff(a, k + 3), wcol[k + 3], g3);
        }
        hsc[(size_t)nd * D + lane] = __float2half(((g0 + g1) + (g2 + g3)) * dinv[nd]);
    }
}

// ---------------- aggregation + epilogue: out = relu(dv*(sum hsc + hsc_self) + b) ------
__device__ __forceinline__ int rlane_i(int v, int l) {
    return __builtin_amdgcn_readlane(v, l);
}

#define GPAIR4(accA, accB, accC, accD, creg, tt)                                   \
    {                                                                              \
        const int sa0 = rlane_i(creg, 2 * (tt) + 0), sb0 = rlane_i(creg, 2 * (tt) + 1); \
        const int sa1 = rlane_i(creg, 2 * (tt) + 2), sb1 = rlane_i(creg, 2 * (tt) + 3); \
        const int sa2 = rlane_i(creg, 2 * (tt) + 4), sb2 = rlane_i(creg, 2 * (tt) + 5); \
        const int sa3 = rlane_i(creg, 2 * (tt) + 6), sb3 = rlane_i(creg, 2 * (tt) + 7); \
        const int s0 = hsel ? sb0 : sa0;                                           \
        const int s1 = hsel ? sb1 : sa1;                                           \
        const int s2 = hsel ? sb2 : sa2;                                           \
        const int s3 = hsel ? sb3 : sa3;                                           \
        const float2 v0 = __half22float2(xh2[(size_t)s0 * 32 + f2]);               \
        const float2 v1 = __half22float2(xh2[(size_t)s1 * 32 + f2]);               \
        const float2 v2 = __half22float2(xh2[(size_t)s2 * 32 + f2]);               \
        const float2 v3 = __half22float2(xh2[(size_t)s3 * 32 + f2]);               \
        accA.x += v0.x; accA.y += v0.y;                                            \
        accB.x += v1.x; accB.y += v1.y;                                            \
        accC.x += v2.x; accC.y += v2.y;                                            \
        accD.x += v3.x; accD.y += v3.y;                                            \
    }

#define GPAIR1(accA, creg, tt)                                                     \
    {                                                                              \
        const int sa = rlane_i(creg, 2 * (tt) + 0), sb = rlane_i(creg, 2 * (tt) + 1);   \
        const int s = hsel ? sb : sa;                                              \
        const float2 v = __half22float2(xh2[(size_t)s * 32 + f2]);                 \
        accA.x += v.x; accA.y += v.y;                                              \
    }

#define GODD(accA, creg, ch)                                                       \
    if ((ch) & 1) {                                                                \
        const int s = rlane_i(creg, (ch) - 1);                                     \
        if (!hsel) {                                                               \
            const float2 v = __half22float2(xh2[(size_t)s * 32 + f2]);             \
            accA.x += v.x; accA.y += v.y;                                          \
        }                                                                          \
    }

template <bool FINAL>
__global__ __launch_bounds__(256) void agg_pair(const __half* __restrict__ hsc,
                                                const int2* __restrict__ rows,
                                                const int* __restrict__ col,
                                                const float* __restrict__ dinv,
                                                const float* __restrict__ bias,
                                                float* __restrict__ outf,
                                                __half* __restrict__ outh, int n) {
    const int gwave = (blockIdx.x * blockDim.x + threadIdx.x) >> 6;
    const int lane = threadIdx.x & 63;
    const int nd0 = gwave * 2;
    if (nd0 >= n) return;
    const int nd1 = nd0 + 1;          // n is even
    const int f2 = lane & 31;
    const int hsel = lane >> 5;
    const __half2* xh2 = (const __half2*)hsc;

    const int2 r0 = rows[nd0];
    const int2 r1 = rows[nd1];
    const int b0 = r0.x, e0 = r0.y;
    const int b1 = r1.x, e1 = r1.y;

    const int ch0 = min(e0 - b0, 64);
    const int ch1 = min(e1 - b1, 64);
    const int c0 = (lane < ch0) ? col[b0 + lane] : 0;   // both chunks in flight
    const int c1 = (lane < ch1) ? col[b1 + lane] : 0;

    float2 A0 = make_float2(0.f, 0.f), A1 = make_float2(0.f, 0.f);
    float2 A2 = make_float2(0.f, 0.f), A3 = make_float2(0.f, 0.f);
    float2 B0 = make_float2(0.f, 0.f), B1 = make_float2(0.f, 0.f);
    float2 B2 = make_float2(0.f, 0.f), B3 = make_float2(0.f, 0.f);

    const int np0 = ch0 >> 1, np1 = ch1 >> 1;
    const int mm = min(np0, np1) & ~3;
    int t = 0;
    for (; t < mm; t += 4) {            // interleaved: 8 loads / 16 edges in flight
        GPAIR4(A0, A1, A2, A3, c0, t)
        GPAIR4(B0, B1, B2, B3, c1, t)
    }
    int t0 = t, t1 = t;
    for (; t0 + 3 < np0; t0 += 4) GPAIR4(A0, A1, A2, A3, c0, t0)
    for (; t0 < np0; ++t0) GPAIR1(A0, c0, t0)
    GODD(A0, c0, ch0)
    for (; t1 + 3 < np1; t1 += 4) GPAIR4(B0, B1, B2, B3, c1, t1)
    for (; t1 < np1; ++t1) GPAIR1(B0, c1, t1)
    GODD(B0, c1, ch1)

    // residual chunks for degree > 64 (essentially never for Poisson(16))
    for (int j = b0 + 64; j < e0; j += 64) {
        const int chunk = min(e0 - j, 64);
        const int c = (lane < chunk) ? col[j + lane] : 0;
        const int np = chunk >> 1;
        int tt = 0;
        for (; tt + 3 < np; tt += 4) GPAIR4(A0, A1, A2, A3, c, tt)
        for (; tt < np; ++tt) GPAIR1(A0, c, tt)
        GODD(A0, c, chunk)
    }
    for (int j = b1 + 64; j < e1; j += 64) {
        const int chunk = min(e1 - j, 64);
        const int c = (lane < chunk) ? col[j + lane] : 0;
        const int np = chunk >> 1;
        int tt = 0;
        for (; tt + 3 < np; tt += 4) GPAIR4(B0, B1, B2, B3, c, tt)
        for (; tt < np; ++tt) GPAIR1(B0, c, tt)
        GODD(B0, c, chunk)
    }

    float2 sA, sB;
    sA.x = (A0.x + A1.x) + (A2.x + A3.x);
    sA.y = (A0.y + A1.y) + (A2.y + A3.y);
    sB.x = (B0.x + B1.x) + (B2.x + B3.x);
    sB.y = (B0.y + B1.y) + (B2.y + B3.y);
    sA.x += __shfl_xor(sA.x, 32, 64);   // combine edge-parity halves
    sA.y += __shfl_xor(sA.y, 32, 64);
    sB.x += __shfl_xor(sB.x, 32, 64);
    sB.y += __shfl_xor(sB.y, 32, 64);

    if (!hsel) {                        // lanes 0..31 write the rows
        const float dv0 = dinv[nd0], dv1 = dinv[nd1];
        const float2 self0 = __half22float2(xh2[(size_t)nd0 * 32 + f2]);
        const float2 self1 = __half22float2(xh2[(size_t)nd1 * 32 + f2]);
        const float2 bv = *(const float2*)(bias + f2 * 2);
        const float r0x = fmaxf(fmaf(dv0, sA.x + self0.x, bv.x), 0.f);
        const float r0y = fmaxf(fmaf(dv0, sA.y + self0.y, bv.y), 0.f);
        const float r1x = fmaxf(fmaf(dv1, sB.x + self1.x, bv.x), 0.f);
        const float r1y = fmaxf(fmaf(dv1, sB.y + self1.y, bv.y), 0.f);
        if (FINAL) {
            float2* o2 = (float2*)outf;
            o2[(size_t)nd0 * 32 + f2] = make_float2(r0x, r0y);
            o2[(size_t)nd1 * 32 + f2] = make_float2(r1x, r1y);
        } else {
            __half2* o2 = (__half2*)outh;
            o2[(size_t)nd0 * 32 + f2] = __floats2half2_rn(r0x, r0y);
            o2[(size_t)nd1 * 32 + f2] = __floats2half2_rn(r1x, r1y);
        }
    }
}

extern "C" void kernel_launch(void* const* d_in, const int* in_sizes, int n_in,
                              void* d_out, int out_size, void* d_ws, size_t ws_size,
                              hipStream_t stream) {
    const float* feature = (const float*)d_in[0];
    const int*   edges   = (const int*)d_in[1];   // [2, E] flat: src then dst
    const float* W1      = (const float*)d_in[2];
    const float* b1      = (const float*)d_in[3];
    const float* W2      = (const float*)d_in[4];
    const float* b2      = (const float*)d_in[5];
    float* out = (float*)d_out;

    const int* src = edges;
    const int* dst = edges + N_EDGES;

    // workspace layout (~42MB)
    char* w = (char*)d_ws;
    int*    cursor = (int*)w;    w += sizeof(int) * (NB * 16);            // padded counters
    int2*   rows   = (int2*)w;   w += sizeof(int2) * (N_NODES);           // 800KB
    float*  dinv   = (float*)w;  w += sizeof(float) * (N_NODES);
    int*    part   = (int*)w;    w += sizeof(int) * (NB * CCAP);          // 7.3MB
    int*    colA   = (int*)w;    w += sizeof(int) * (NB * CCAP);          // 7.3MB
    __half* hsc    = (__half*)w; w += sizeof(__half) * ((size_t)N_NODES * D);  // 12.8MB
    __half* y1h    = (__half*)w; w += sizeof(__half) * ((size_t)N_NODES * D);  // 12.8MB

    // ---- front-end: zero cursors (own kernel, not rocclr fill), reserve+partition, sort
    zero_cursor<<<4, 1024, 0, stream>>>(cursor);
    partition_fused<<<NBLK, 1024, 0, stream>>>(src, dst, cursor, part);
    bucket_csr<<<NB_USED, 512, 0, stream>>>(cursor, part, colA, rows, dinv);

    const int pair_blocks = (N_NODES / 2 + 3) / 4;   // 2 nodes/wave, 4 waves/block

    // ---- layer 1: hsc = dinv*(x@W1); y1 = relu(A_hat-sum + b1) ----
    gemm_pre<false><<<2048, 256, 0, stream>>>(feature, W1, dinv, hsc, N_NODES);
    agg_pair<false><<<pair_blocks, 256, 0, stream>>>(hsc, rows, colA, dinv, b1,
                                                     nullptr, y1h, N_NODES);

    // ---- layer 2: hsc = dinv*(y1@W2); out = relu(A_hat-sum + b2) ----
    gemm_pre<true><<<2048, 256, 0, stream>>>(y1h, W2, dinv, hsc, N_NODES);
    agg_pair<true><<<pair_blocks, 256, 0, stream>>>(hsc, rows, colA, dinv, b2,
                                                    out, nullptr, N_NODES);
}

// Round 21
// 167.329 us; speedup vs baseline: 1.4162x; 1.0020x over previous
//
#include <hip/hip_runtime.h>
#include <hip/hip_fp16.h>

#define N_NODES 100000
#define N_EDGES 1600000
#define D 64

#define NB 256                  // fat buckets
#define BUCKET_W 391            // nodes per bucket (256*391 = 100096 >= 100000)
#define NB_USED 256
#define NBLK 256                // partition blocks
#define CHUNK ((N_EDGES + NBLK - 1) / NBLK)             // 6250
#define CCAP 7168               // fixed bucket capacity (mean 6250, sd ~79 -> 11 sigma)
#define LMASK 511               // 9-bit local node index

// ---------------- zero the reservation cursors (4096 ints) ----------------
__global__ __launch_bounds__(1024) void zero_cursor(int* __restrict__ p) {
    p[blockIdx.x * 1024 + threadIdx.x] = 0;
}

// ---------------- fused count+reserve+scatter: one pass, no scan kernel ----------------
__global__ __launch_bounds__(1024) void partition_fused(const int* __restrict__ src,
                                                        const int* __restrict__ dst,
                                                        int* __restrict__ cursor,
                                                        int* __restrict__ part) {
    __shared__ int h[NB];
    __shared__ int lcur[NB];
    const int t = threadIdx.x;
    if (t < NB) h[t] = 0;
    __syncthreads();
    const int blk = blockIdx.x;
    const int beg = blk * CHUNK;
    const int end = min(beg + CHUNK, N_EDGES);
    for (int e = beg + t; e < end; e += 1024)
        atomicAdd(&h[dst[e] / BUCKET_W], 1);
    __syncthreads();
    if (t < NB) {
        const int c = h[t];
        const int base = c ? atomicAdd(&cursor[t * 16], c) : 0;   // padded counter line
        lcur[t] = t * CCAP + base;
    }
    __syncthreads();
    for (int e = beg + t; e < end; e += 1024) {
        const int d = dst[e];
        const int s = src[e];
        const int b = d / BUCKET_W;
        const int pos = atomicAdd(&lcur[b], 1);         // LDS atomic
        part[pos] = (s << 9) | (d - b * BUCKET_W);
    }
}

// ---------------- pass C: counting sort (parallel scan) -> col, rows, dinv -------------
__global__ __launch_bounds__(512) void bucket_csr(const int* __restrict__ cursor,
                                                  const int* __restrict__ part,
                                                  int* __restrict__ col,
                                                  int2* __restrict__ rows,
                                                  float* __restrict__ dinv) {
    __shared__ int ed[CCAP];
    __shared__ int hist[BUCKET_W];
    __shared__ int lcur[BUCKET_W];
    __shared__ int sc[512];
    const int b = blockIdx.x;
    const int base = b * CCAP;
    const int cnt = min(cursor[b * 16], CCAP);
    const int n0 = b * BUCKET_W;
    const int nn = min(N_NODES - n0, BUCKET_W);
    const int t = threadIdx.x;

    if (t < BUCKET_W) hist[t] = 0;
    for (int i = t; i < cnt; i += 512) ed[i] = part[base + i];
    __syncthreads();
    for (int i = t; i < cnt; i += 512) atomicAdd(&hist[ed[i] & LMASK], 1);
    __syncthreads();
    // parallel exclusive scan of hist[0..nn) (nn <= 391 < 512)
    const int v = (t < nn) ? hist[t] : 0;
    sc[t] = v;
    __syncthreads();
    for (int off = 1; off < 512; off <<= 1) {
        int u = (t >= off) ? sc[t - off] : 0;
        __syncthreads();
        sc[t] += u;
        __syncthreads();
    }
    if (t < nn) {
        const int excl = sc[t] - v;
        lcur[t] = base + excl;
        rows[n0 + t] = make_int2(base + excl, base + excl + v);
        dinv[n0 + t] = rsqrtf((float)v + 1.0f);
    }
    __syncthreads();
    for (int i = t; i < cnt; i += 512) {
        const int p = ed[i];
        const int pos = atomicAdd(&lcur[p & LMASK], 1);
        col[pos] = p >> 9;
    }
}

// ---------------- gemm_pre: hsc[nd] = dinv[nd] * (x[nd] @ W)  [fp16 out] ----------------
__device__ __forceinline__ float rlane_ff(float v, int l) {
    return __int_as_float(__builtin_amdgcn_readlane(__float_as_int(v), l));
}

template <bool IN_HALF>
__global__ __launch_bounds__(256) void gemm_pre(const void* __restrict__ xin,
                                                const float* __restrict__ W,
                                                const float* __restrict__ dinv,
                                                __half* __restrict__ hsc, int n) {
    const int lane = threadIdx.x & 63;
    const int gwave = (blockIdx.x * blockDim.x + threadIdx.x) >> 6;
    const int nwaves = (gridDim.x * blockDim.x) >> 6;
    float wcol[64];
#pragma unroll
    for (int k = 0; k < 64; ++k) wcol[k] = W[k * 64 + lane];

    for (int nd = gwave; nd < n; nd += nwaves) {
        float a;
        if (IN_HALF) a = __half2float(((const __half*)xin)[(size_t)nd * D + lane]);
        else         a = ((const float*)xin)[(size_t)nd * D + lane];
        float g0 = 0.f, g1 = 0.f, g2 = 0.f, g3 = 0.f;
#pragma unroll
        for (int k = 0; k < 64; k += 4) {
            g0 = fmaf(rlane_ff(a, k + 0), wcol[k + 0], g0);
            g1 = fmaf(rlane_ff(a, k + 1), wcol[k + 1], g1);
            g2 = fmaf(rlane_ff(a, k + 2), wcol[k + 2], g2);
            g3 = fmaf(rlane_ff(a, k + 3), wcol[k + 3], g3);
        }
        hsc[(size_t)nd * D + lane] = __float2half(((g0 + g1) + (g2 + g3)) * dinv[nd]);
    }
}

// ---------------- aggregation + epilogue: out = relu(dv*(sum hsc + hsc_self) + b) ------
// v_fma_mix_f32 accumulates an fp16 half directly into an fp32 register (cvt+add in one
// instruction): 2 VALU per gathered half2 instead of 4 (2 cvt + 2 add).
__device__ __forceinline__ int rlane_i(int v, int l) {
    return __builtin_amdgcn_readlane(v, l);
}

__device__ __forceinline__ void acc_h2(float& ax, float& ay, unsigned int h) {
    asm("v_fma_mix_f32 %0, %1, 1.0, %0 op_sel_hi:[1,0,0]" : "+v"(ax) : "v"(h));
    asm("v_fma_mix_f32 %0, %1, 1.0, %0 op_sel:[1,0,0] op_sel_hi:[1,0,0]" : "+v"(ay) : "v"(h));
}

#define GPAIR4(accA, accB, accC, accD, creg, tt)                                   \
    {                                                                              \
        const int sa0 = rlane_i(creg, 2 * (tt) + 0), sb0 = rlane_i(creg, 2 * (tt) + 1); \
        const int sa1 = rlane_i(creg, 2 * (tt) + 2), sb1 = rlane_i(creg, 2 * (tt) + 3); \
        const int sa2 = rlane_i(creg, 2 * (tt) + 4), sb2 = rlane_i(creg, 2 * (tt) + 5); \
        const int sa3 = rlane_i(creg, 2 * (tt) + 6), sb3 = rlane_i(creg, 2 * (tt) + 7); \
        const int s0 = hsel ? sb0 : sa0;                                           \
        const int s1 = hsel ? sb1 : sa1;                                           \
        const int s2 = hsel ? sb2 : sa2;                                           \
        const int s3 = hsel ? sb3 : sa3;                                           \
        const unsigned int v0 = xu[(size_t)s0 * 32 + f2];                          \
        const unsigned int v1 = xu[(size_t)s1 * 32 + f2];                          \
        const unsigned int v2 = xu[(size_t)s2 * 32 + f2];                          \
        const unsigned int v3 = xu[(size_t)s3 * 32 + f2];                          \
        acc_h2(accA.x, accA.y, v0);                                                \
        acc_h2(accB.x, accB.y, v1);                                                \
        acc_h2(accC.x, accC.y, v2);                                                \
        acc_h2(accD.x, accD.y, v3);                                                \
    }

#define GPAIR1(accA, creg, tt)                                                     \
    {                                                                              \
        const int sa = rlane_i(creg, 2 * (tt) + 0), sb = rlane_i(creg, 2 * (tt) + 1);   \
        const int s = hsel ? sb : sa;                                              \
        const unsigned int v = xu[(size_t)s * 32 + f2];                            \
        acc_h2(accA.x, accA.y, v);                                                 \
    }

#define GODD(accA, creg, ch)                                                       \
    if ((ch) & 1) {                                                                \
        const int s = rlane_i(creg, (ch) - 1);                                     \
        if (!hsel) {                                                               \
            const unsigned int v = xu[(size_t)s * 32 + f2];                        \
            acc_h2(accA.x, accA.y, v);                                             \
        }                                                                          \
    }

template <bool FINAL>
__global__ __launch_bounds__(256) void agg_pair(const __half* __restrict__ hsc,
                                                const int2* __restrict__ rows,
                                                const int* __restrict__ col,
                                                const float* __restrict__ dinv,
                                                const float* __restrict__ bias,
                                                float* __restrict__ outf,
                                                __half* __restrict__ outh, int n) {
    const int gwave = (blockIdx.x * blockDim.x + threadIdx.x) >> 6;
    const int lane = threadIdx.x & 63;
    const int nd0 = gwave * 2;
    if (nd0 >= n) return;
    const int nd1 = nd0 + 1;          // n is even
    const int f2 = lane & 31;
    const int hsel = lane >> 5;
    const unsigned int* xu = (const unsigned int*)hsc;
    const __half2* xh2 = (const __half2*)hsc;

    const int2 r0 = rows[nd0];
    const int2 r1 = rows[nd1];
    const int b0 = r0.x, e0 = r0.y;
    const int b1 = r1.x, e1 = r1.y;

    const int ch0 = min(e0 - b0, 64);
    const int ch1 = min(e1 - b1, 64);
    const int c0 = (lane < ch0) ? col[b0 + lane] : 0;   // both chunks in flight
    const int c1 = (lane < ch1) ? col[b1 + lane] : 0;

    float2 A0 = make_float2(0.f, 0.f), A1 = make_float2(0.f, 0.f);
    float2 A2 = make_float2(0.f, 0.f), A3 = make_float2(0.f, 0.f);
    float2 B0 = make_float2(0.f, 0.f), B1 = make_float2(0.f, 0.f);
    float2 B2 = make_float2(0.f, 0.f), B3 = make_float2(0.f, 0.f);

    const int np0 = ch0 >> 1, np1 = ch1 >> 1;
    const int mm = min(np0, np1) & ~3;
    int t = 0;
    for (; t < mm; t += 4) {            // interleaved: 8 loads / 16 edges in flight
        GPAIR4(A0, A1, A2, A3, c0, t)
        GPAIR4(B0, B1, B2, B3, c1, t)
    }
    int t0 = t, t1 = t;
    for (; t0 + 3 < np0; t0 += 4) GPAIR4(A0, A1, A2, A3, c0, t0)
    for (; t0 < np0; ++t0) GPAIR1(A0, c0, t0)
    GODD(A0, c0, ch0)
    for (; t1 + 3 < np1; t1 += 4) GPAIR4(B0, B1, B2, B3, c1, t1)
    for (; t1 < np1; ++t1) GPAIR1(B0, c1, t1)
    GODD(B0, c1, ch1)

    // residual chunks for degree > 64 (essentially never for Poisson(16))
    for (int j = b0 + 64; j < e0; j += 64) {
        const int chunk = min(e0 - j, 64);
        const int c = (lane < chunk) ? col[j + lane] : 0;
        const int np = chunk >> 1;
        int tt = 0;
        for (; tt + 3 < np; tt += 4) GPAIR4(A0, A1, A2, A3, c, tt)
        for (; tt < np; ++tt) GPAIR1(A0, c, tt)
        GODD(A0, c, chunk)
    }
    for (int j = b1 + 64; j < e1; j += 64) {
        const int chunk = min(e1 - j, 64);
        const int c = (lane < chunk) ? col[j + lane] : 0;
        const int np = chunk >> 1;
        int tt = 0;
        for (; tt + 3 < np; tt += 4) GPAIR4(B0, B1, B2, B3, c, tt)
        for (; tt < np; ++tt) GPAIR1(B0, c, tt)
        GODD(B0, c, chunk)
    }

    float2 sA, sB;
    sA.x = (A0.x + A1.x) + (A2.x + A3.x);
    sA.y = (A0.y + A1.y) + (A2.y + A3.y);
    sB.x = (B0.x + B1.x) + (B2.x + B3.x);
    sB.y = (B0.y + B1.y) + (B2.y + B3.y);
    sA.x += __shfl_xor(sA.x, 32, 64);   // combine edge-parity halves
    sA.y += __shfl_xor(sA.y, 32, 64);
    sB.x += __shfl_xor(sB.x, 32, 64);
    sB.y += __shfl_xor(sB.y, 32, 64);

    if (!hsel) {                        // lanes 0..31 write the rows
        const float dv0 = dinv[nd0], dv1 = dinv[nd1];
        const float2 self0 = __half22float2(xh2[(size_t)nd0 * 32 + f2]);
        const float2 self1 = __half22float2(xh2[(size_t)nd1 * 32 + f2]);
        const float2 bv = *(const float2*)(bias + f2 * 2);
        const float r0x = fmaxf(fmaf(dv0, sA.x + self0.x, bv.x), 0.f);
        const float r0y = fmaxf(fmaf(dv0, sA.y + self0.y, bv.y), 0.f);
        const float r1x = fmaxf(fmaf(dv1, sB.x + self1.x, bv.x), 0.f);
        const float r1y = fmaxf(fmaf(dv1, sB.y + self1.y, bv.y), 0.f);
        if (FINAL) {
            float2* o2 = (float2*)outf;
            o2[(size_t)nd0 * 32 + f2] = make_float2(r0x, r0y);
            o2[(size_t)nd1 * 32 + f2] = make_float2(r1x, r1y);
        } else {
            __half2* o2 = (__half2*)outh;
            o2[(size_t)nd0 * 32 + f2] = __floats2half2_rn(r0x, r0y);
            o2[(size_t)nd1 * 32 + f2] = __floats2half2_rn(r1x, r1y);
        }
    }
}

extern "C" void kernel_launch(void* const* d_in, const int* in_sizes, int n_in,
                              void* d_out, int out_size, void* d_ws, size_t ws_size,
                              hipStream_t stream) {
    const float* feature = (const float*)d_in[0];
    const int*   edges   = (const int*)d_in[1];   // [2, E] flat: src then dst
    const float* W1      = (const float*)d_in[2];
    const float* b1      = (const float*)d_in[3];
    const float* W2      = (const float*)d_in[4];
    const float* b2      = (const float*)d_in[5];
    float* out = (float*)d_out;

    const int* src = edges;
    const int* dst = edges + N_EDGES;

    // workspace layout (~42MB)
    char* w = (char*)d_ws;
    int*    cursor = (int*)w;    w += sizeof(int) * (NB * 16);            // padded counters
    int2*   rows   = (int2*)w;   w += sizeof(int2) * (N_NODES);           // 800KB
    float*  dinv   = (float*)w;  w += sizeof(float) * (N_NODES);
    int*    part   = (int*)w;    w += sizeof(int) * (NB * CCAP);          // 7.3MB
    int*    colA   = (int*)w;    w += sizeof(int) * (NB * CCAP);          // 7.3MB
    __half* hsc    = (__half*)w; w += sizeof(__half) * ((size_t)N_NODES * D);  // 12.8MB
    __half* y1h    = (__half*)w; w += sizeof(__half) * ((size_t)N_NODES * D);  // 12.8MB

    // ---- front-end: zero cursors, reserve+partition, sort (once) ----
    zero_cursor<<<4, 1024, 0, stream>>>(cursor);
    partition_fused<<<NBLK, 1024, 0, stream>>>(src, dst, cursor, part);
    bucket_csr<<<NB_USED, 512, 0, stream>>>(cursor, part, colA, rows, dinv);

    const int pair_blocks = (N_NODES / 2 + 3) / 4;   // 2 nodes/wave, 4 waves/block

    // ---- layer 1: hsc = dinv*(x@W1); y1 = relu(A_hat-sum + b1) ----
    gemm_pre<false><<<2048, 256, 0, stream>>>(feature, W1, dinv, hsc, N_NODES);
    agg_pair<false><<<pair_blocks, 256, 0, stream>>>(hsc, rows, colA, dinv, b1,
                                                     nullptr, y1h, N_NODES);

    // ---- layer 2: hsc = dinv*(y1@W2); out = relu(A_hat-sum + b2) ----
    gemm_pre<true><<<2048, 256, 0, stream>>>(y1h, W2, dinv, hsc, N_NODES);
    agg_pair<true><<<pair_blocks, 256, 0, stream>>>(hsc, rows, colA, dinv, b2,
                                                    out, nullptr, N_NODES);
}